// Round 9
// baseline (827.366 us; speedup 1.0000x reference)
//
#include <hip/hip_runtime.h>
#include <hip/hip_cooperative_groups.h>
#include <cstdint>
#include <cstddef>

namespace cg = cooperative_groups;

#define CHUNK 4096

typedef __attribute__((ext_vector_type(8))) short short8;
typedef __attribute__((ext_vector_type(4))) float f32x4;

__device__ __forceinline__ float bf2f(unsigned short u) {
  return __uint_as_float(((unsigned)u) << 16);
}
__device__ __forceinline__ unsigned short f2bf(float f) {
  unsigned u = __float_as_uint(f);
  u += 0x7fffu + ((u >> 16) & 1u);   // RNE
  return (unsigned short)(u >> 16);
}

// ---------------- prep: W transpose->bf16 + zero gcur + zero pool ----------------
__global__ void prep_k(const float* __restrict__ W1, const float* __restrict__ W2,
                       unsigned short* __restrict__ W1t, unsigned short* __restrict__ W2t,
                       int* __restrict__ gcur, int B, float* __restrict__ pool, int poolN) {
  int idx = blockIdx.x * 256 + threadIdx.x;   // grid 128
  const float* W = (idx < 16384) ? W1 : W2;
  unsigned short* Wt = (idx < 16384) ? W1t : W2t;
  int i = idx & 16383;
  int k = i >> 7, n = i & 127;
  Wt[n * 128 + k] = f2bf(W[i]);
  if (blockIdx.x == 0 && threadIdx.x < B) gcur[threadIdx.x] = 0;
  if (blockIdx.x == 127)
    for (int j = threadIdx.x; j < poolN; j += 256) pool[j] = 0.f;
}

// ---------------- single-pass bucket scatter ----------------
__global__ __launch_bounds__(256) void scatter_atomic_k(const int* __restrict__ src,
                                                        const int* __restrict__ dst, int E,
                                                        int* __restrict__ gcur,
                                                        unsigned int* __restrict__ tmp,
                                                        int cap, int B) {
  __shared__ unsigned pk[CHUNK];
  __shared__ unsigned char bk[CHUNK];
  __shared__ int h[256];
  __shared__ int cur[256];
  __shared__ int base_s[256];
  int t = threadIdx.x;
  h[t] = 0;
  __syncthreads();
  int e0 = blockIdx.x * CHUNK;
  int e1 = e0 + CHUNK; if (e1 > E) e1 = E;
  int m = e1 - e0;
  for (int i = t; i < m; i += 256) {
    int d = dst[e0 + i], s = src[e0 + i];
    int b = d >> 8;
    pk[i] = ((unsigned)s << 8) | (unsigned)(d & 255);
    bk[i] = (unsigned char)b;
    atomicAdd(&h[b], 1);
  }
  __syncthreads();
  if (t < B && h[t] > 0) base_s[t] = atomicAdd(&gcur[t], h[t]);
  cur[t] = 0;
  __syncthreads();
  for (int i = t; i < m; i += 256) {
    int b = bk[i];
    int r = atomicAdd(&cur[b], 1);
    int p = base_s[b] + r;
    if (p < cap) tmp[(size_t)b * cap + p] = pk[i];
  }
}

// ---------------- cooperative mega-kernel: cntfill -> gemm1 -> agg1 -> gemm2 -> agg2 -> pool -> classify
struct CoopArgs {
  const float* x;
  const unsigned short* W1t; const unsigned short* W2t;
  const float* b1; const float* b2;
  const int* gcur; const unsigned* tmp; int cap; int B;
  float* dinv; int* rs; unsigned short* col;
  unsigned short* B2; unsigned short* B3;
  const int* bat; float* pool; float* gcnt;
  const float* Wc1; const float* bc1; const float* Wc2; const float* bc2;
  float* out;
  int N; int E; int NC; int G; int ntiles; int naggq;
};

union SMem {
  unsigned short ws[128 * 136];                 // 34816 B (gemm stage + epilogue)
  struct { int c[256]; int cur[256]; int sb[256]; } cf;
  struct { float gs[128]; float zs[128]; } cl;
};

template <bool AF32>
__device__ __forceinline__ void gemm_tile(SMem& sm, const void* Ap,
                                          const unsigned short* Wt,
                                          unsigned short* C, int N, int tile) {
  for (int idx = threadIdx.x; idx < 2048; idx += 256) {
    int n = idx >> 4, c = idx & 15;
    *(uint4*)&sm.ws[n * 136 + c * 8] = ((const uint4*)Wt)[idx];
  }
  __syncthreads();
  const int w = threadIdx.x >> 6;
  const int lane = threadIdx.x & 63;
  const int quad = lane >> 4, l16 = lane & 15;
  const int rb = tile * 128 + w * 32;
  f32x4 acc[2][8] = {};
  #pragma unroll
  for (int ks = 0; ks < 4; ks++) {
    short8 aF[2];
    #pragma unroll
    for (int m = 0; m < 2; m++) {
      int r = rb + m * 16 + l16;
      short8 a = {};
      if (r < N) {
        if (AF32) {
          const float* ar = (const float*)Ap + (size_t)r * 128 + ks * 32 + quad * 8;
          float4 u0 = *(const float4*)ar;
          float4 u1 = *(const float4*)(ar + 4);
          a[0] = (short)f2bf(u0.x); a[1] = (short)f2bf(u0.y);
          a[2] = (short)f2bf(u0.z); a[3] = (short)f2bf(u0.w);
          a[4] = (short)f2bf(u1.x); a[5] = (short)f2bf(u1.y);
          a[6] = (short)f2bf(u1.z); a[7] = (short)f2bf(u1.w);
        } else {
          a = *(const short8*)((const unsigned short*)Ap + (size_t)r * 128 + ks * 32 + quad * 8);
        }
      }
      aF[m] = a;
    }
    #pragma unroll
    for (int t = 0; t < 8; t++) {
      short8 bF = *(const short8*)&sm.ws[(t * 16 + l16) * 136 + ks * 32 + quad * 8];
      acc[0][t] = __builtin_amdgcn_mfma_f32_16x16x32_bf16(aF[0], bF, acc[0][t], 0, 0, 0);
      acc[1][t] = __builtin_amdgcn_mfma_f32_16x16x32_bf16(aF[1], bF, acc[1][t], 0, 0, 0);
    }
  }
  __syncthreads();
  unsigned short* Cs = sm.ws;
  #pragma unroll
  for (int m = 0; m < 2; m++) {
    int rloc = w * 32 + m * 16 + quad * 4;
    #pragma unroll
    for (int t = 0; t < 8; t++)
      #pragma unroll
      for (int rg = 0; rg < 4; rg++)
        Cs[(rloc + rg) * 132 + t * 16 + l16] = f2bf(acc[m][t][rg]);
  }
  __syncthreads();
  const int r0 = tile * 128;
  for (int idx = threadIdx.x; idx < 2048; idx += 256) {
    int row = idx >> 4, c = idx & 15;
    int rr = r0 + row;
    if (rr < N) {
      uint2 a = *(uint2*)&Cs[row * 132 + c * 8];
      uint2 b = *(uint2*)&Cs[row * 132 + c * 8 + 4];
      ((uint4*)C)[(size_t)rr * 16 + c] = make_uint4(a.x, a.y, b.x, b.y);
    }
  }
  __syncthreads();   // Cs reads done before next tile restages (safety for loops)
}

__device__ __forceinline__ void agg_node(const unsigned short* h, const int* rs,
                                         const unsigned short* col, const float* dinv,
                                         const float* bias, unsigned short* outp,
                                         int n, int wid, int lane) {
  const int g = lane >> 4;
  const int l = lane & 15;
  float di = dinv[wid];
  float acc[8];
  {
    uint4 sv = ((const uint4*)(h + (size_t)wid * 128))[l];
    float ws = (g == 0) ? di : 0.f;
    acc[0] = bf2f((unsigned short)sv.x) * ws;
    acc[1] = bf2f((unsigned short)(sv.x >> 16)) * ws;
    acc[2] = bf2f((unsigned short)sv.y) * ws;
    acc[3] = bf2f((unsigned short)(sv.y >> 16)) * ws;
    acc[4] = bf2f((unsigned short)sv.z) * ws;
    acc[5] = bf2f((unsigned short)(sv.z >> 16)) * ws;
    acc[6] = bf2f((unsigned short)sv.w) * ws;
    acc[7] = bf2f((unsigned short)(sv.w >> 16)) * ws;
  }
  int beg = rs[wid], end = rs[wid + 1];
  for (int base = beg; base < end; base += 8) {
    int e0 = base + g, e1 = base + 4 + g;
    int i0 = (e0 < end) ? e0 : end - 1;
    int i1 = (e1 < end) ? e1 : end - 1;
    int s0 = (int)col[i0], s1 = (int)col[i1];
    float w0 = (e0 < end) ? dinv[s0] : 0.f;
    float w1 = (e1 < end) ? dinv[s1] : 0.f;
    uint4 h0 = ((const uint4*)(h + (size_t)s0 * 128))[l];
    uint4 h1 = ((const uint4*)(h + (size_t)s1 * 128))[l];
    acc[0] += bf2f((unsigned short)h0.x) * w0 + bf2f((unsigned short)h1.x) * w1;
    acc[1] += bf2f((unsigned short)(h0.x >> 16)) * w0 + bf2f((unsigned short)(h1.x >> 16)) * w1;
    acc[2] += bf2f((unsigned short)h0.y) * w0 + bf2f((unsigned short)h1.y) * w1;
    acc[3] += bf2f((unsigned short)(h0.y >> 16)) * w0 + bf2f((unsigned short)(h1.y >> 16)) * w1;
    acc[4] += bf2f((unsigned short)h0.z) * w0 + bf2f((unsigned short)h1.z) * w1;
    acc[5] += bf2f((unsigned short)(h0.z >> 16)) * w0 + bf2f((unsigned short)(h1.z >> 16)) * w1;
    acc[6] += bf2f((unsigned short)h0.w) * w0 + bf2f((unsigned short)h1.w) * w1;
    acc[7] += bf2f((unsigned short)(h0.w >> 16)) * w0 + bf2f((unsigned short)(h1.w >> 16)) * w1;
  }
  #pragma unroll
  for (int j = 0; j < 8; j++) {
    acc[j] += __shfl_xor(acc[j], 16);
    acc[j] += __shfl_xor(acc[j], 32);
  }
  if (g == 0) {
    float4 bA = *(const float4*)(bias + l * 8);
    float4 bB = *(const float4*)(bias + l * 8 + 4);
    float r0 = fmaxf(acc[0] * di + bA.x, 0.f);
    float r1 = fmaxf(acc[1] * di + bA.y, 0.f);
    float r2 = fmaxf(acc[2] * di + bA.z, 0.f);
    float r3 = fmaxf(acc[3] * di + bA.w, 0.f);
    float r4 = fmaxf(acc[4] * di + bB.x, 0.f);
    float r5 = fmaxf(acc[5] * di + bB.y, 0.f);
    float r6 = fmaxf(acc[6] * di + bB.z, 0.f);
    float r7 = fmaxf(acc[7] * di + bB.w, 0.f);
    uint4 v;
    v.x = (unsigned)f2bf(r0) | ((unsigned)f2bf(r1) << 16);
    v.y = (unsigned)f2bf(r2) | ((unsigned)f2bf(r3) << 16);
    v.z = (unsigned)f2bf(r4) | ((unsigned)f2bf(r5) << 16);
    v.w = (unsigned)f2bf(r6) | ((unsigned)f2bf(r7) << 16);
    ((uint4*)outp)[(size_t)wid * 16 + l] = v;
  }
}

__global__ __launch_bounds__(256, 4) void coop_k(CoopArgs a) {
  cg::grid_group gg = cg::this_grid();
  __shared__ SMem sm;
  const int t = threadIdx.x;

  // ---- P0: per-bucket cntfill (with in-block bucket_base scan) ----
  if ((int)blockIdx.x < a.B) {
    int b = blockIdx.x;
    int cb = 0;
    if (t < a.B) { cb = a.gcur[t]; if (cb > a.cap) cb = a.cap; }
    sm.cf.sb[t] = cb;
    __syncthreads();
    for (int off = 1; off < 256; off <<= 1) {
      int u = (t >= off) ? sm.cf.sb[t - off] : 0;
      __syncthreads();
      sm.cf.sb[t] += u;
      __syncthreads();
    }
    int base_b = (b > 0) ? sm.cf.sb[b - 1] : 0;
    int cnt_b = sm.cf.sb[b] - base_b;
    if (b == 0 && t == 0) a.rs[a.N] = sm.cf.sb[a.B - 1];   // true total (robust to cap clip)
    const unsigned* tb = a.tmp + (size_t)b * a.cap;
    sm.cf.c[t] = 0;
    __syncthreads();
    for (int i = t; i < cnt_b; i += 256) atomicAdd(&sm.cf.c[tb[i] & 255u], 1);
    __syncthreads();
    int v = sm.cf.c[t];
    sm.cf.cur[t] = v;
    __syncthreads();
    for (int off = 1; off < 256; off <<= 1) {
      int u = (t >= off) ? sm.cf.cur[t - off] : 0;
      __syncthreads();
      sm.cf.cur[t] += u;
      __syncthreads();
    }
    int rsv = base_b + sm.cf.cur[t] - v;
    int node = (b << 8) + t;
    if (node < a.N) {
      a.rs[node] = rsv;
      a.dinv[node] = rsqrtf((float)v + 1.0f);
    }
    __syncthreads();
    sm.cf.cur[t] = rsv;
    __syncthreads();
    for (int i = t; i < cnt_b; i += 256) {
      unsigned u = tb[i];
      int pos = atomicAdd(&sm.cf.cur[u & 255u], 1);
      a.col[pos] = (unsigned short)(u >> 8);
    }
  }
  gg.sync();

  // ---- P1: gemm1 (x fp32 -> B2) ----
  for (int tile = blockIdx.x; tile < a.ntiles; tile += gridDim.x)
    gemm_tile<true>(sm, a.x, a.W1t, a.B2, a.N, tile);
  gg.sync();

  // ---- P2: agg1 (B2 -> B3) ----
  {
    int lane = t & 63, wv = t >> 6;
    for (int q = blockIdx.x; q < a.naggq; q += gridDim.x) {
      int wid = q * 4 + wv;
      if (wid < a.N) agg_node(a.B2, a.rs, a.col, a.dinv, a.b1, a.B3, a.N, wid, lane);
    }
  }
  gg.sync();

  // ---- P3: gemm2 (B3 -> B2) ----
  for (int tile = blockIdx.x; tile < a.ntiles; tile += gridDim.x)
    gemm_tile<false>(sm, a.B3, a.W2t, a.B2, a.N, tile);
  gg.sync();

  // ---- P4: agg2 (B2 -> B3) ----
  {
    int lane = t & 63, wv = t >> 6;
    for (int q = blockIdx.x; q < a.naggq; q += gridDim.x) {
      int wid = q * 4 + wv;
      if (wid < a.N) agg_node(a.B2, a.rs, a.col, a.dinv, a.b2, a.B3, a.N, wid, lane);
    }
  }
  gg.sync();

  // ---- P5: pool (bf16 B3 -> pool/gcnt; pool pre-zeroed in prep_k) ----
  {
    int hf = t >> 7;            // two 128-thread halves per block
    int f = t & 127;
    int nchunks = (a.N + 63) / 64;
    for (int c = blockIdx.x * 2 + hf; c < nchunks; c += gridDim.x * 2) {
      int n0 = c * 64;
      int n1 = n0 + 64; if (n1 > a.N) n1 = a.N;
      int gcur_ = a.bat[n0];
      float acc = 0.f, cacc = 0.f;
      for (int i = n0; i < n1; i++) {
        int g = a.bat[i];
        if (g != gcur_) {
          atomicAdd(&a.pool[gcur_ * 128 + f], acc);
          if (f == 0) atomicAdd(&a.gcnt[gcur_], cacc);
          acc = 0.f; cacc = 0.f; gcur_ = g;
        }
        acc += bf2f(a.B3[(size_t)i * 128 + f]);
        cacc += 1.f;
      }
      atomicAdd(&a.pool[gcur_ * 128 + f], acc);
      if (f == 0) atomicAdd(&a.gcnt[gcur_], cacc);
    }
  }
  gg.sync();

  // ---- P6: classifier head ----
  if ((int)blockIdx.x < a.G) {
    int g = blockIdx.x;
    if (t < 128) {
      float c = a.gcnt[g]; if (c < 1.f) c = 1.f;
      sm.cl.gs[t] = a.pool[g * 128 + t] / c;
    }
    __syncthreads();
    if (t < 128) {
      float acc = a.bc1[t];
      for (int k = 0; k < 128; k++) acc += sm.cl.gs[k] * a.Wc1[k * 128 + t];
      sm.cl.zs[t] = fmaxf(acc, 0.f);
    }
    __syncthreads();
    if (t < a.NC) {
      float o = a.bc2[t];
      for (int k = 0; k < 128; k++) o += sm.cl.zs[k] * a.Wc2[k * a.NC + t];
      a.out[g * a.NC + t] = o;
    }
  }
}

// ---------------- fallback path kernels (N > 65535) ----------------
__global__ void count_edges_k(const int* __restrict__ dst, int E, int* __restrict__ cnt) {
  int e = blockIdx.x * blockDim.x + threadIdx.x;
  if (e < E) atomicAdd(&cnt[dst[e]], 1);
}
__global__ void dinv_k(const int* __restrict__ cnt, float* __restrict__ dinv, int n) {
  int i = blockIdx.x * blockDim.x + threadIdx.x;
  if (i < n) dinv[i] = rsqrtf((float)cnt[i] + 1.0f);
}
__global__ void fill_csr_k(const int* __restrict__ src, const int* __restrict__ dst, int E,
                           int* __restrict__ cursor, int* __restrict__ col) {
  int e = blockIdx.x * blockDim.x + threadIdx.x;
  if (e < E) {
    int d = dst[e], s = src[e];
    int pos = atomicAdd(&cursor[d], 1);
    col[pos] = s;
  }
}
__global__ void scan1_k(const int* __restrict__ cnt, int* __restrict__ rs,
                        int* __restrict__ partials, int n) {
  __shared__ int s[1024];
  int t = threadIdx.x;
  int gid = blockIdx.x * 1024 + t;
  int v = (gid < n) ? cnt[gid] : 0;
  s[t] = v;
  __syncthreads();
  for (int off = 1; off < 1024; off <<= 1) {
    int u = (t >= off) ? s[t - off] : 0;
    __syncthreads();
    s[t] += u;
    __syncthreads();
  }
  if (gid < n) rs[gid] = s[t] - v;
  if (t == 1023) partials[blockIdx.x] = s[1023];
}
__global__ void scan2_k(int* __restrict__ partials, int nb) {
  if (threadIdx.x == 0 && blockIdx.x == 0) {
    int acc = 0;
    for (int i = 0; i < nb; i++) { int v = partials[i]; partials[i] = acc; acc += v; }
  }
}
__global__ void scan3_k(int* __restrict__ rs, int* __restrict__ cursor,
                        const int* __restrict__ partials, int n, int total) {
  int gid = blockIdx.x * blockDim.x + threadIdx.x;
  if (gid < n) {
    int v = rs[gid] + partials[gid >> 10];
    rs[gid] = v;
    cursor[gid] = v;
  }
  if (gid == 0) rs[n] = total;
}
template <bool AF32>
__global__ __launch_bounds__(256) void gemm_bf_k(const void* __restrict__ Ap,
                                                 const unsigned short* __restrict__ Wt,
                                                 unsigned short* __restrict__ C, int N) {
  __shared__ SMem sm;
  gemm_tile<AF32>(sm, Ap, Wt, C, N, blockIdx.x);
}
__global__ __launch_bounds__(256) void agg8i_k(const unsigned short* __restrict__ h,
                                               const int* __restrict__ rs,
                                               const int* __restrict__ col,
                                               const float* __restrict__ dinv,
                                               const float* __restrict__ bias,
                                               unsigned short* __restrict__ outp, int n) {
  int wid = (blockIdx.x * blockDim.x + threadIdx.x) >> 6;
  int lane = threadIdx.x & 63;
  if (wid >= n) return;
  const int g = lane >> 4, l = lane & 15;
  float di = dinv[wid];
  float acc[8];
  uint4 sv = ((const uint4*)(h + (size_t)wid * 128))[l];
  float ws = (g == 0) ? di : 0.f;
  acc[0] = bf2f((unsigned short)sv.x) * ws; acc[1] = bf2f((unsigned short)(sv.x >> 16)) * ws;
  acc[2] = bf2f((unsigned short)sv.y) * ws; acc[3] = bf2f((unsigned short)(sv.y >> 16)) * ws;
  acc[4] = bf2f((unsigned short)sv.z) * ws; acc[5] = bf2f((unsigned short)(sv.z >> 16)) * ws;
  acc[6] = bf2f((unsigned short)sv.w) * ws; acc[7] = bf2f((unsigned short)(sv.w >> 16)) * ws;
  int beg = rs[wid], end = rs[wid + 1];
  for (int base = beg; base < end; base += 8) {
    int e0 = base + g, e1 = base + 4 + g;
    int i0 = (e0 < end) ? e0 : end - 1;
    int i1 = (e1 < end) ? e1 : end - 1;
    int s0 = col[i0], s1 = col[i1];
    float w0 = (e0 < end) ? dinv[s0] : 0.f;
    float w1 = (e1 < end) ? dinv[s1] : 0.f;
    uint4 h0 = ((const uint4*)(h + (size_t)s0 * 128))[l];
    uint4 h1 = ((const uint4*)(h + (size_t)s1 * 128))[l];
    acc[0] += bf2f((unsigned short)h0.x) * w0 + bf2f((unsigned short)h1.x) * w1;
    acc[1] += bf2f((unsigned short)(h0.x >> 16)) * w0 + bf2f((unsigned short)(h1.x >> 16)) * w1;
    acc[2] += bf2f((unsigned short)h0.y) * w0 + bf2f((unsigned short)h1.y) * w1;
    acc[3] += bf2f((unsigned short)(h0.y >> 16)) * w0 + bf2f((unsigned short)(h1.y >> 16)) * w1;
    acc[4] += bf2f((unsigned short)h0.z) * w0 + bf2f((unsigned short)h1.z) * w1;
    acc[5] += bf2f((unsigned short)(h0.z >> 16)) * w0 + bf2f((unsigned short)(h1.z >> 16)) * w1;
    acc[6] += bf2f((unsigned short)h0.w) * w0 + bf2f((unsigned short)h1.w) * w1;
    acc[7] += bf2f((unsigned short)(h0.w >> 16)) * w0 + bf2f((unsigned short)(h1.w >> 16)) * w1;
  }
  #pragma unroll
  for (int j = 0; j < 8; j++) { acc[j] += __shfl_xor(acc[j], 16); acc[j] += __shfl_xor(acc[j], 32); }
  if (g == 0) {
    float4 bA = *(const float4*)(bias + l * 8);
    float4 bB = *(const float4*)(bias + l * 8 + 4);
    uint4 v;
    v.x = (unsigned)f2bf(fmaxf(acc[0] * di + bA.x, 0.f)) | ((unsigned)f2bf(fmaxf(acc[1] * di + bA.y, 0.f)) << 16);
    v.y = (unsigned)f2bf(fmaxf(acc[2] * di + bA.z, 0.f)) | ((unsigned)f2bf(fmaxf(acc[3] * di + bA.w, 0.f)) << 16);
    v.z = (unsigned)f2bf(fmaxf(acc[4] * di + bB.x, 0.f)) | ((unsigned)f2bf(fmaxf(acc[5] * di + bB.y, 0.f)) << 16);
    v.w = (unsigned)f2bf(fmaxf(acc[6] * di + bB.z, 0.f)) | ((unsigned)f2bf(fmaxf(acc[7] * di + bB.w, 0.f)) << 16);
    ((uint4*)outp)[(size_t)wid * 16 + l] = v;
  }
}
__global__ void poolb_k(const unsigned short* __restrict__ h, const int* __restrict__ batch, int n,
                        float* __restrict__ pool, float* __restrict__ gcnt) {
  int f = threadIdx.x;
  int n0 = blockIdx.x * 64;
  if (n0 >= n) return;
  int n1 = n0 + 64; if (n1 > n) n1 = n;
  int gcur = batch[n0];
  float acc = 0.f, cacc = 0.f;
  for (int i = n0; i < n1; i++) {
    int g = batch[i];
    if (g != gcur) {
      atomicAdd(&pool[gcur * 128 + f], acc);
      if (f == 0) atomicAdd(&gcnt[gcur], cacc);
      acc = 0.f; cacc = 0.f; gcur = g;
    }
    acc += bf2f(h[(size_t)i * 128 + f]);
    cacc += 1.f;
  }
  atomicAdd(&pool[gcur * 128 + f], acc);
  if (f == 0) atomicAdd(&gcnt[gcur], cacc);
}
__global__ void classify_k(const float* __restrict__ pool, const float* __restrict__ gcnt,
                           const float* __restrict__ Wc1, const float* __restrict__ bc1,
                           const float* __restrict__ Wc2, const float* __restrict__ bc2,
                           float* __restrict__ out, int nc) {
  __shared__ float gs[128];
  __shared__ float zs[128];
  int g = blockIdx.x, t = threadIdx.x;
  float c = gcnt[g]; if (c < 1.f) c = 1.f;
  gs[t] = pool[g * 128 + t] / c;
  __syncthreads();
  float acc = bc1[t];
  for (int k = 0; k < 128; k++) acc += gs[k] * Wc1[k * 128 + t];
  zs[t] = fmaxf(acc, 0.f);
  __syncthreads();
  if (t < nc) {
    float o = bc2[t];
    for (int k = 0; k < 128; k++) o += zs[k] * Wc2[k * nc + t];
    out[g * nc + t] = o;
  }
}

extern "C" void kernel_launch(void* const* d_in, const int* in_sizes, int n_in,
                              void* d_out, int out_size, void* d_ws, size_t ws_size,
                              hipStream_t stream) {
  const float* x   = (const float*)d_in[0];
  const int*   ei  = (const int*)d_in[1];
  const int*   bat = (const int*)d_in[2];
  const float* W1  = (const float*)d_in[3];
  const float* b1  = (const float*)d_in[4];
  const float* W2  = (const float*)d_in[5];
  const float* b2  = (const float*)d_in[6];
  const float* Wc1 = (const float*)d_in[7];
  const float* bc1 = (const float*)d_in[8];
  const float* Wc2 = (const float*)d_in[9];
  const float* bc2 = (const float*)d_in[10];
  float* out = (float*)d_out;

  const int N  = in_sizes[0] / 128;
  const int E  = in_sizes[1] / 2;
  const int NC = in_sizes[10];
  const int G  = out_size / NC;
  const int* src = ei;
  const int* dst = ei + E;
  (void)n_in; (void)ws_size;

  size_t off = 0;
  auto walloc = [&](size_t bytes) -> void* {
    void* p = (char*)d_ws + off;
    off += (bytes + 255) & ~(size_t)255;
    return p;
  };
  unsigned short* B2 = (unsigned short*)walloc((size_t)N * 128 * 2);
  unsigned short* B3 = (unsigned short*)walloc((size_t)N * 128 * 2);
  unsigned short* W1t = (unsigned short*)walloc(128 * 128 * 2);
  unsigned short* W2t = (unsigned short*)walloc(128 * 128 * 2);
  float* dinv = (float*)walloc((size_t)N * 4);
  int*   rs   = (int*)  walloc((size_t)(N + 1) * 4);
  float* pool = (float*)walloc((size_t)G * 129 * 4);
  float* gcnt = pool + (size_t)G * 128;

  const bool small = (N <= 65535);

  if (small) {
    const int B    = (N + 255) >> 8;
    const int nblk = (E + CHUNK - 1) / CHUNK;
    const int cap  = (E + B - 1) / B + 2048;
    unsigned short* col = (unsigned short*)walloc((size_t)E * 2);
    unsigned int*   tmp = (unsigned int*)  walloc((size_t)B * cap * 4);
    int* gcur = (int*)walloc((size_t)B * 4);

    prep_k<<<128, 256, 0, stream>>>(W1, W2, W1t, W2t, gcur, B, pool, G * 129);
    scatter_atomic_k<<<nblk, 256, 0, stream>>>(src, dst, E, gcur, tmp, cap, B);

    CoopArgs ca;
    ca.x = x; ca.W1t = W1t; ca.W2t = W2t; ca.b1 = b1; ca.b2 = b2;
    ca.gcur = gcur; ca.tmp = tmp; ca.cap = cap; ca.B = B;
    ca.dinv = dinv; ca.rs = rs; ca.col = col;
    ca.B2 = B2; ca.B3 = B3;
    ca.bat = bat; ca.pool = pool; ca.gcnt = gcnt;
    ca.Wc1 = Wc1; ca.bc1 = bc1; ca.Wc2 = Wc2; ca.bc2 = bc2;
    ca.out = out;
    ca.N = N; ca.E = E; ca.NC = NC; ca.G = G;
    ca.ntiles = (N + 127) / 128;
    ca.naggq = (N + 3) / 4;

    int nbpc = 0;
    hipOccupancyMaxActiveBlocksPerMultiprocessor(&nbpc, (const void*)coop_k, 256, 0);
    if (nbpc < 1) nbpc = 1;
    int numCU = 0;
    hipDeviceGetAttribute(&numCU, hipDeviceAttributeMultiprocessorCount, 0);
    if (numCU < 1) numCU = 256;
    int grid = nbpc * numCU;
    if (grid < B) grid = B;          // P0 needs >= B blocks (one bucket per block)
    if (grid < G) grid = G;          // P6 needs >= G blocks
    void* args[] = { &ca };
    hipLaunchCooperativeKernel((const void*)coop_k, dim3(grid), dim3(256), args, 0, stream);
  } else {
    const int nb = (N + 1023) / 1024;
    const int gblocks = (N + 127) / 128;
    const int aggGrid = (N + 3) / 4;
    int* cnt    = (int*)walloc((size_t)N * 4);
    int* cursor = (int*)walloc((size_t)N * 4);
    int* col    = (int*)walloc((size_t)E * 4);
    int* partials = (int*)walloc(256 * 4);
    prep_k<<<128, 256, 0, stream>>>(W1, W2, W1t, W2t, cnt /*dummy*/, 0, pool, G * 129);
    hipMemsetAsync(cnt, 0, (size_t)N * 4, stream);
    count_edges_k<<<(E + 255) / 256, 256, 0, stream>>>(dst, E, cnt);
    scan1_k<<<nb, 1024, 0, stream>>>(cnt, rs, partials, N);
    scan2_k<<<1, 64, 0, stream>>>(partials, nb);
    scan3_k<<<(N + 255) / 256, 256, 0, stream>>>(rs, cursor, partials, N, E);
    dinv_k<<<(N + 255) / 256, 256, 0, stream>>>(cnt, dinv, N);
    fill_csr_k<<<(E + 255) / 256, 256, 0, stream>>>(src, dst, E, cursor, (int*)col);

    gemm_bf_k<true><<<gblocks, 256, 0, stream>>>(x, W1t, B2, N);
    agg8i_k<<<aggGrid, 256, 0, stream>>>(B2, rs, (int*)col, dinv, b1, B3, N);
    gemm_bf_k<false><<<gblocks, 256, 0, stream>>>(B3, W2t, B2, N);
    agg8i_k<<<aggGrid, 256, 0, stream>>>(B2, rs, (int*)col, dinv, b2, B3, N);

    poolb_k<<<(N + 63) / 64, 128, 0, stream>>>(B3, bat, N, pool, gcnt);
    classify_k<<<G, 128, 0, stream>>>(pool, gcnt, Wc1, bc1, Wc2, bc2, out, NC);
  }
}

// Round 10
// 384.333 us; speedup vs baseline: 2.1527x; 2.1527x over previous
//
#include <hip/hip_runtime.h>
#include <cstdint>
#include <cstddef>

#define CHUNK 4096

typedef __attribute__((ext_vector_type(8))) short short8;
typedef __attribute__((ext_vector_type(4))) float f32x4;

__device__ __forceinline__ float bf2f(unsigned short u) {
  return __uint_as_float(((unsigned)u) << 16);
}
__device__ __forceinline__ unsigned short f2bf(float f) {
  unsigned u = __float_as_uint(f);
  u += 0x7fffu + ((u >> 16) & 1u);   // RNE
  return (unsigned short)(u >> 16);
}

// shared-memory overlay: gemm staging vs cntfill scratch
union SMem {
  unsigned short ws[128 * 136];                          // 34816 B
  struct { int c[256]; int cur[256]; int sb[256]; } cf;  // 3 KB
};

// ---------------- prep: W transpose -> bf16 (Wt[n][k]) + zero gcur ----------------
__global__ void prep_k(const float* __restrict__ W1, const float* __restrict__ W2,
                       unsigned short* __restrict__ W1t, unsigned short* __restrict__ W2t,
                       int* __restrict__ gcur, int B) {
  int idx = blockIdx.x * 256 + threadIdx.x;   // grid 128
  const float* W = (idx < 16384) ? W1 : W2;
  unsigned short* Wt = (idx < 16384) ? W1t : W2t;
  int i = idx & 16383;
  int k = i >> 7, n = i & 127;
  Wt[n * 128 + k] = f2bf(W[i]);
  if (blockIdx.x == 0 && threadIdx.x < B) gcur[threadIdx.x] = 0;
}

// ---------------- single-pass bucket scatter (N <= 65535) ----------------
__global__ __launch_bounds__(256) void scatter_atomic_k(const int* __restrict__ src,
                                                        const int* __restrict__ dst, int E,
                                                        int* __restrict__ gcur,
                                                        unsigned int* __restrict__ tmp,
                                                        int cap, int B) {
  __shared__ unsigned pk[CHUNK];
  __shared__ unsigned char bk[CHUNK];
  __shared__ int h[256];
  __shared__ int cur[256];
  __shared__ int base_s[256];
  int t = threadIdx.x;
  h[t] = 0;
  __syncthreads();
  int e0 = blockIdx.x * CHUNK;
  int e1 = e0 + CHUNK; if (e1 > E) e1 = E;
  int m = e1 - e0;
  for (int i = t; i < m; i += 256) {
    int d = dst[e0 + i], s = src[e0 + i];
    int b = d >> 8;
    pk[i] = ((unsigned)s << 8) | (unsigned)(d & 255);
    bk[i] = (unsigned char)b;
    atomicAdd(&h[b], 1);
  }
  __syncthreads();
  if (t < B && h[t] > 0) base_s[t] = atomicAdd(&gcur[t], h[t]);
  cur[t] = 0;
  __syncthreads();
  for (int i = t; i < m; i += 256) {
    int b = bk[i];
    int r = atomicAdd(&cur[b], 1);
    int p = base_s[b] + r;
    if (p < cap) tmp[(size_t)b * cap + p] = pk[i];
  }
}

// ---------------- gemm tile body (device fn, used by fused + standalone) ----------------
template <bool AF32>
__device__ __forceinline__ void gemm_tile(SMem& sm, const void* Ap,
                                          const unsigned short* Wt,
                                          unsigned short* C, int N, int tile) {
  for (int idx = threadIdx.x; idx < 2048; idx += 256) {
    int n = idx >> 4, c = idx & 15;
    *(uint4*)&sm.ws[n * 136 + c * 8] = ((const uint4*)Wt)[idx];
  }
  __syncthreads();
  const int w = threadIdx.x >> 6;
  const int lane = threadIdx.x & 63;
  const int quad = lane >> 4, l16 = lane & 15;
  const int rb = tile * 128 + w * 32;
  f32x4 acc[2][8] = {};
  #pragma unroll
  for (int ks = 0; ks < 4; ks++) {
    short8 aF[2];
    #pragma unroll
    for (int m = 0; m < 2; m++) {
      int r = rb + m * 16 + l16;
      short8 a = {};
      if (r < N) {
        if (AF32) {
          const float* ar = (const float*)Ap + (size_t)r * 128 + ks * 32 + quad * 8;
          float4 u0 = *(const float4*)ar;
          float4 u1 = *(const float4*)(ar + 4);
          a[0] = (short)f2bf(u0.x); a[1] = (short)f2bf(u0.y);
          a[2] = (short)f2bf(u0.z); a[3] = (short)f2bf(u0.w);
          a[4] = (short)f2bf(u1.x); a[5] = (short)f2bf(u1.y);
          a[6] = (short)f2bf(u1.z); a[7] = (short)f2bf(u1.w);
        } else {
          a = *(const short8*)((const unsigned short*)Ap + (size_t)r * 128 + ks * 32 + quad * 8);
        }
      }
      aF[m] = a;
    }
    #pragma unroll
    for (int t = 0; t < 8; t++) {
      short8 bF = *(const short8*)&sm.ws[(t * 16 + l16) * 136 + ks * 32 + quad * 8];
      acc[0][t] = __builtin_amdgcn_mfma_f32_16x16x32_bf16(aF[0], bF, acc[0][t], 0, 0, 0);
      acc[1][t] = __builtin_amdgcn_mfma_f32_16x16x32_bf16(aF[1], bF, acc[1][t], 0, 0, 0);
    }
  }
  __syncthreads();
  unsigned short* Cs = sm.ws;
  #pragma unroll
  for (int m = 0; m < 2; m++) {
    int rloc = w * 32 + m * 16 + quad * 4;
    #pragma unroll
    for (int t = 0; t < 8; t++)
      #pragma unroll
      for (int rg = 0; rg < 4; rg++)
        Cs[(rloc + rg) * 132 + t * 16 + l16] = f2bf(acc[m][t][rg]);
  }
  __syncthreads();
  const int r0 = tile * 128;
  for (int idx = threadIdx.x; idx < 2048; idx += 256) {
    int row = idx >> 4, c = idx & 15;
    int rr = r0 + row;
    if (rr < N) {
      uint2 a = *(uint2*)&Cs[row * 132 + c * 8];
      uint2 b = *(uint2*)&Cs[row * 132 + c * 8 + 4];
      ((uint4*)C)[(size_t)rr * 16 + c] = make_uint4(a.x, a.y, b.x, b.y);
    }
  }
}

// ---------------- fused: cntfill (blocks [0,B)) + gemm1 (blocks [B, B+ntiles)) ----------------
// independent work items; no cross-dependency.
__global__ __launch_bounds__(256) void cntfill_gemm1_k(const unsigned int* __restrict__ tmp,
                                                       const int* __restrict__ gcur,
                                                       int N, int E, int cap, int B,
                                                       float* __restrict__ dinv,
                                                       int* __restrict__ rs,
                                                       unsigned short* __restrict__ col,
                                                       const float* __restrict__ x,
                                                       const unsigned short* __restrict__ W1t,
                                                       unsigned short* __restrict__ B2) {
  __shared__ SMem sm;
  const int t = threadIdx.x;
  if ((int)blockIdx.x >= B) {
    gemm_tile<true>(sm, x, W1t, B2, N, blockIdx.x - B);
    return;
  }
  // --- cntfill with inline bucket-base scan ---
  int b = blockIdx.x;
  int cb = 0;
  if (t < B) { cb = gcur[t]; if (cb > cap) cb = cap; }
  sm.cf.sb[t] = cb;
  __syncthreads();
  for (int off = 1; off < 256; off <<= 1) {
    int u = (t >= off) ? sm.cf.sb[t - off] : 0;
    __syncthreads();
    sm.cf.sb[t] += u;
    __syncthreads();
  }
  int base_b = (b > 0) ? sm.cf.sb[b - 1] : 0;
  int cnt_b = sm.cf.sb[b] - base_b;
  if (b == 0 && t == 0) rs[N] = sm.cf.sb[B - 1];
  const unsigned* tb = tmp + (size_t)b * cap;
  sm.cf.c[t] = 0;
  __syncthreads();
  for (int i = t; i < cnt_b; i += 256) atomicAdd(&sm.cf.c[tb[i] & 255u], 1);
  __syncthreads();
  int v = sm.cf.c[t];
  sm.cf.cur[t] = v;
  __syncthreads();
  for (int off = 1; off < 256; off <<= 1) {
    int u = (t >= off) ? sm.cf.cur[t - off] : 0;
    __syncthreads();
    sm.cf.cur[t] += u;
    __syncthreads();
  }
  int rsv = base_b + sm.cf.cur[t] - v;
  int node = (b << 8) + t;
  if (node < N) {
    rs[node] = rsv;
    dinv[node] = rsqrtf((float)v + 1.0f);
  }
  __syncthreads();
  sm.cf.cur[t] = rsv;
  __syncthreads();
  for (int i = t; i < cnt_b; i += 256) {
    unsigned u = tb[i];
    int pos = atomicAdd(&sm.cf.cur[u & 255u], 1);
    col[pos] = (unsigned short)(u >> 8);
  }
}

// standalone gemm (layer 2 + fallback layer 1)
template <bool AF32>
__global__ __launch_bounds__(256) void gemm_bf_k(const void* __restrict__ Ap,
                                                 const unsigned short* __restrict__ Wt,
                                                 unsigned short* __restrict__ C, int N) {
  __shared__ SMem sm;
  gemm_tile<AF32>(sm, Ap, Wt, C, N, blockIdx.x);
}

// ---------------- aggregation: 16 lanes/edge, 8 edges in flight (row-major bf16) ----------------
template <typename CT>
__global__ __launch_bounds__(256) void agg8_k(const unsigned short* __restrict__ h,
                                              const int* __restrict__ rs,
                                              const CT* __restrict__ col,
                                              const float* __restrict__ dinv,
                                              const float* __restrict__ bias,
                                              unsigned short* __restrict__ outp, int n) {
  int wid = (blockIdx.x * blockDim.x + threadIdx.x) >> 6;
  int lane = threadIdx.x & 63;
  if (wid >= n) return;
  const int g = lane >> 4;
  const int l = lane & 15;
  float di = dinv[wid];
  float acc[8];
  {
    uint4 sv = ((const uint4*)(h + (size_t)wid * 128))[l];
    float ws = (g == 0) ? di : 0.f;
    acc[0] = bf2f((unsigned short)sv.x) * ws;
    acc[1] = bf2f((unsigned short)(sv.x >> 16)) * ws;
    acc[2] = bf2f((unsigned short)sv.y) * ws;
    acc[3] = bf2f((unsigned short)(sv.y >> 16)) * ws;
    acc[4] = bf2f((unsigned short)sv.z) * ws;
    acc[5] = bf2f((unsigned short)(sv.z >> 16)) * ws;
    acc[6] = bf2f((unsigned short)sv.w) * ws;
    acc[7] = bf2f((unsigned short)(sv.w >> 16)) * ws;
  }
  int beg = rs[wid], end = rs[wid + 1];
  for (int base = beg; base < end; base += 8) {
    int e0 = base + g, e1 = base + 4 + g;
    int i0 = (e0 < end) ? e0 : end - 1;
    int i1 = (e1 < end) ? e1 : end - 1;
    int s0 = (int)col[i0], s1 = (int)col[i1];
    float w0 = (e0 < end) ? dinv[s0] : 0.f;
    float w1 = (e1 < end) ? dinv[s1] : 0.f;
    uint4 h0 = ((const uint4*)(h + (size_t)s0 * 128))[l];
    uint4 h1 = ((const uint4*)(h + (size_t)s1 * 128))[l];
    acc[0] += bf2f((unsigned short)h0.x) * w0 + bf2f((unsigned short)h1.x) * w1;
    acc[1] += bf2f((unsigned short)(h0.x >> 16)) * w0 + bf2f((unsigned short)(h1.x >> 16)) * w1;
    acc[2] += bf2f((unsigned short)h0.y) * w0 + bf2f((unsigned short)h1.y) * w1;
    acc[3] += bf2f((unsigned short)(h0.y >> 16)) * w0 + bf2f((unsigned short)(h1.y >> 16)) * w1;
    acc[4] += bf2f((unsigned short)h0.z) * w0 + bf2f((unsigned short)h1.z) * w1;
    acc[5] += bf2f((unsigned short)(h0.z >> 16)) * w0 + bf2f((unsigned short)(h1.z >> 16)) * w1;
    acc[6] += bf2f((unsigned short)h0.w) * w0 + bf2f((unsigned short)h1.w) * w1;
    acc[7] += bf2f((unsigned short)(h0.w >> 16)) * w0 + bf2f((unsigned short)(h1.w >> 16)) * w1;
  }
  #pragma unroll
  for (int j = 0; j < 8; j++) {
    acc[j] += __shfl_xor(acc[j], 16);
    acc[j] += __shfl_xor(acc[j], 32);
  }
  if (g == 0) {
    float4 bA = *(const float4*)(bias + l * 8);
    float4 bB = *(const float4*)(bias + l * 8 + 4);
    float r0 = fmaxf(acc[0] * di + bA.x, 0.f);
    float r1 = fmaxf(acc[1] * di + bA.y, 0.f);
    float r2 = fmaxf(acc[2] * di + bA.z, 0.f);
    float r3 = fmaxf(acc[3] * di + bA.w, 0.f);
    float r4 = fmaxf(acc[4] * di + bB.x, 0.f);
    float r5 = fmaxf(acc[5] * di + bB.y, 0.f);
    float r6 = fmaxf(acc[6] * di + bB.z, 0.f);
    float r7 = fmaxf(acc[7] * di + bB.w, 0.f);
    uint4 v;
    v.x = (unsigned)f2bf(r0) | ((unsigned)f2bf(r1) << 16);
    v.y = (unsigned)f2bf(r2) | ((unsigned)f2bf(r3) << 16);
    v.z = (unsigned)f2bf(r4) | ((unsigned)f2bf(r5) << 16);
    v.w = (unsigned)f2bf(r6) | ((unsigned)f2bf(r7) << 16);
    ((uint4*)outp)[(size_t)wid * 16 + l] = v;
  }
}

// ---------------- fused mean-pool + classifier: one block per graph ----------------
// batch is sorted: block g binary-searches its node range, sums locally (no atomics,
// no pool scratch), then runs the 2-layer head.
__global__ __launch_bounds__(256) void poolclassify_k(const unsigned short* __restrict__ h,
                                                      const int* __restrict__ bat, int n,
                                                      const float* __restrict__ Wc1,
                                                      const float* __restrict__ bc1,
                                                      const float* __restrict__ Wc2,
                                                      const float* __restrict__ bc2,
                                                      float* __restrict__ out, int nc) {
  __shared__ float gs[128];
  __shared__ float part[128];
  __shared__ float zs[128];
  const int g = blockIdx.x;
  const int t = threadIdx.x;
  // lower_bound(bat, g) and lower_bound(bat, g+1)
  int lo;
  {
    int l = 0, r = n;
    while (l < r) { int m = (l + r) >> 1; if (bat[m] < g) l = m + 1; else r = m; }
    lo = l;
  }
  int hi;
  {
    int l = lo, r = n;
    while (l < r) { int m = (l + r) >> 1; if (bat[m] < g + 1) l = m + 1; else r = m; }
    hi = l;
  }
  const int f = t & 127;
  const int half = t >> 7;     // 2 nodes in flight
  float acc = 0.f;
  for (int i = lo + half; i < hi; i += 2)
    acc += bf2f(h[(size_t)i * 128 + f]);
  if (half == 1) part[f] = acc;
  __syncthreads();
  if (half == 0) {
    float c = (float)(hi - lo); if (c < 1.f) c = 1.f;
    gs[f] = (acc + part[f]) / c;
  }
  __syncthreads();
  if (t < 128) {
    float a = bc1[t];
    for (int k = 0; k < 128; k++) a += gs[k] * Wc1[k * 128 + t];
    zs[t] = fmaxf(a, 0.f);
  }
  __syncthreads();
  if (t < nc) {
    float o = bc2[t];
    for (int k = 0; k < 128; k++) o += zs[k] * Wc2[k * nc + t];
    out[g * nc + t] = o;
  }
}

// ---------------- fallback CSR build (N > 65535) ----------------
__global__ void count_edges_k(const int* __restrict__ dst, int E, int* __restrict__ cnt) {
  int e = blockIdx.x * blockDim.x + threadIdx.x;
  if (e < E) atomicAdd(&cnt[dst[e]], 1);
}
__global__ void dinv_k(const int* __restrict__ cnt, float* __restrict__ dinv, int n) {
  int i = blockIdx.x * blockDim.x + threadIdx.x;
  if (i < n) dinv[i] = rsqrtf((float)cnt[i] + 1.0f);
}
__global__ void fill_csr_k(const int* __restrict__ src, const int* __restrict__ dst, int E,
                           int* __restrict__ cursor, int* __restrict__ col) {
  int e = blockIdx.x * blockDim.x + threadIdx.x;
  if (e < E) {
    int d = dst[e], s = src[e];
    int pos = atomicAdd(&cursor[d], 1);
    col[pos] = s;
  }
}
__global__ void scan1_k(const int* __restrict__ cnt, int* __restrict__ rs,
                        int* __restrict__ partials, int n) {
  __shared__ int s[1024];
  int t = threadIdx.x;
  int gid = blockIdx.x * 1024 + t;
  int v = (gid < n) ? cnt[gid] : 0;
  s[t] = v;
  __syncthreads();
  for (int off = 1; off < 1024; off <<= 1) {
    int u = (t >= off) ? s[t - off] : 0;
    __syncthreads();
    s[t] += u;
    __syncthreads();
  }
  if (gid < n) rs[gid] = s[t] - v;
  if (t == 1023) partials[blockIdx.x] = s[1023];
}
__global__ void scan2_k(int* __restrict__ partials, int nb) {
  if (threadIdx.x == 0 && blockIdx.x == 0) {
    int acc = 0;
    for (int i = 0; i < nb; i++) { int v = partials[i]; partials[i] = acc; acc += v; }
  }
}
__global__ void scan3_k(int* __restrict__ rs, int* __restrict__ cursor,
                        const int* __restrict__ partials, int n, int total) {
  int gid = blockIdx.x * blockDim.x + threadIdx.x;
  if (gid < n) {
    int v = rs[gid] + partials[gid >> 10];
    rs[gid] = v;
    cursor[gid] = v;
  }
  if (gid == 0) rs[n] = total;
}

extern "C" void kernel_launch(void* const* d_in, const int* in_sizes, int n_in,
                              void* d_out, int out_size, void* d_ws, size_t ws_size,
                              hipStream_t stream) {
  const float* x   = (const float*)d_in[0];
  const int*   ei  = (const int*)d_in[1];
  const int*   bat = (const int*)d_in[2];
  const float* W1  = (const float*)d_in[3];
  const float* b1  = (const float*)d_in[4];
  const float* W2  = (const float*)d_in[5];
  const float* b2  = (const float*)d_in[6];
  const float* Wc1 = (const float*)d_in[7];
  const float* bc1 = (const float*)d_in[8];
  const float* Wc2 = (const float*)d_in[9];
  const float* bc2 = (const float*)d_in[10];
  float* out = (float*)d_out;

  const int N  = in_sizes[0] / 128;
  const int E  = in_sizes[1] / 2;
  const int NC = in_sizes[10];
  const int G  = out_size / NC;
  const int* src = ei;
  const int* dst = ei + E;
  (void)n_in; (void)ws_size;

  size_t off = 0;
  auto walloc = [&](size_t bytes) -> void* {
    void* p = (char*)d_ws + off;
    off += (bytes + 255) & ~(size_t)255;
    return p;
  };
  unsigned short* B2 = (unsigned short*)walloc((size_t)N * 128 * 2);
  unsigned short* B3 = (unsigned short*)walloc((size_t)N * 128 * 2);
  unsigned short* W1t = (unsigned short*)walloc(128 * 128 * 2);
  unsigned short* W2t = (unsigned short*)walloc(128 * 128 * 2);
  float* dinv = (float*)walloc((size_t)N * 4);
  int*   rs   = (int*)  walloc((size_t)(N + 1) * 4);

  const bool small = (N <= 65535);
  const int gblocks = (N + 127) / 128;
  const int aggGrid = (N + 3) / 4;

  if (small) {
    const int B    = (N + 255) >> 8;
    const int nblk = (E + CHUNK - 1) / CHUNK;
    const int cap  = (E + B - 1) / B + 2048;
    unsigned short* col = (unsigned short*)walloc((size_t)E * 2);
    unsigned int*   tmp = (unsigned int*)  walloc((size_t)B * cap * 4);
    int* gcur = (int*)walloc((size_t)B * 4);

    prep_k<<<128, 256, 0, stream>>>(W1, W2, W1t, W2t, gcur, B);
    scatter_atomic_k<<<nblk, 256, 0, stream>>>(src, dst, E, gcur, tmp, cap, B);
    cntfill_gemm1_k<<<B + gblocks, 256, 0, stream>>>(tmp, gcur, N, E, cap, B,
                                                     dinv, rs, col, x, W1t, B2);
    agg8_k<unsigned short><<<aggGrid, 256, 0, stream>>>(B2, rs, col, dinv, b1, B3, N);
    gemm_bf_k<false><<<gblocks, 256, 0, stream>>>(B3, W2t, B2, N);
    agg8_k<unsigned short><<<aggGrid, 256, 0, stream>>>(B2, rs, col, dinv, b2, B3, N);
    poolclassify_k<<<G, 256, 0, stream>>>(B3, bat, N, Wc1, bc1, Wc2, bc2, out, NC);
  } else {
    const int nb = (N + 1023) / 1024;
    int* cnt    = (int*)walloc((size_t)N * 4);
    int* cursor = (int*)walloc((size_t)N * 4);
    int* col    = (int*)walloc((size_t)E * 4);
    int* partials = (int*)walloc(256 * 4);
    prep_k<<<128, 256, 0, stream>>>(W1, W2, W1t, W2t, cnt /*dummy*/, 0);
    hipMemsetAsync(cnt, 0, (size_t)N * 4, stream);
    count_edges_k<<<(E + 255) / 256, 256, 0, stream>>>(dst, E, cnt);
    scan1_k<<<nb, 1024, 0, stream>>>(cnt, rs, partials, N);
    scan2_k<<<1, 64, 0, stream>>>(partials, nb);
    scan3_k<<<(N + 255) / 256, 256, 0, stream>>>(rs, cursor, partials, N, E);
    dinv_k<<<(N + 255) / 256, 256, 0, stream>>>(cnt, dinv, N);
    fill_csr_k<<<(E + 255) / 256, 256, 0, stream>>>(src, dst, E, cursor, col);

    gemm_bf_k<true><<<gblocks, 256, 0, stream>>>(x, W1t, B2, N);
    agg8_k<int><<<aggGrid, 256, 0, stream>>>(B2, rs, col, dinv, b1, B3, N);
    gemm_bf_k<false><<<gblocks, 256, 0, stream>>>(B3, W2t, B2, N);
    agg8_k<int><<<aggGrid, 256, 0, stream>>>(B2, rs, col, dinv, b2, B3, N);
    poolclassify_k<<<G, 256, 0, stream>>>(B3, bat, N, Wc1, bc1, Wc2, bc2, out, NC);
  }
}

// Round 11
// 301.397 us; speedup vs baseline: 2.7451x; 1.2752x over previous
//
#include <hip/hip_runtime.h>
#include <cstdint>
#include <cstddef>

#define CHUNK 4096

typedef __attribute__((ext_vector_type(8))) short short8;
typedef __attribute__((ext_vector_type(4))) float f32x4;

__device__ __forceinline__ float bf2f(unsigned short u) {
  return __uint_as_float(((unsigned)u) << 16);
}
__device__ __forceinline__ unsigned short f2bf(float f) {
  unsigned u = __float_as_uint(f);
  u += 0x7fffu + ((u >> 16) & 1u);   // RNE
  return (unsigned short)(u >> 16);
}

// shared-memory overlay: gemm staging vs cntfill scratch
union SMem {
  unsigned short ws[128 * 136];                          // 34816 B
  struct { int c[256]; int cur[256]; int sb[256]; } cf;  // 3 KB
};

// ---------------- prep: W transpose -> bf16 + zero gcur + zero pool/gcnt ----------------
__global__ void prep_k(const float* __restrict__ W1, const float* __restrict__ W2,
                       unsigned short* __restrict__ W1t, unsigned short* __restrict__ W2t,
                       int* __restrict__ gcur, int B, float* __restrict__ pool, int poolN) {
  int idx = blockIdx.x * 256 + threadIdx.x;   // grid 128
  const float* W = (idx < 16384) ? W1 : W2;
  unsigned short* Wt = (idx < 16384) ? W1t : W2t;
  int i = idx & 16383;
  int k = i >> 7, n = i & 127;
  Wt[n * 128 + k] = f2bf(W[i]);
  if (blockIdx.x == 0 && threadIdx.x < B) gcur[threadIdx.x] = 0;
  if (blockIdx.x == 127)
    for (int j = threadIdx.x; j < poolN; j += 256) pool[j] = 0.f;
}

// ---------------- single-pass bucket scatter (N <= 65535) ----------------
__global__ __launch_bounds__(256) void scatter_atomic_k(const int* __restrict__ src,
                                                        const int* __restrict__ dst, int E,
                                                        int* __restrict__ gcur,
                                                        unsigned int* __restrict__ tmp,
                                                        int cap, int B) {
  __shared__ unsigned pk[CHUNK];
  __shared__ unsigned char bk[CHUNK];
  __shared__ int h[256];
  __shared__ int cur[256];
  __shared__ int base_s[256];
  int t = threadIdx.x;
  h[t] = 0;
  __syncthreads();
  int e0 = blockIdx.x * CHUNK;
  int e1 = e0 + CHUNK; if (e1 > E) e1 = E;
  int m = e1 - e0;
  for (int i = t; i < m; i += 256) {
    int d = dst[e0 + i], s = src[e0 + i];
    int b = d >> 8;
    pk[i] = ((unsigned)s << 8) | (unsigned)(d & 255);
    bk[i] = (unsigned char)b;
    atomicAdd(&h[b], 1);
  }
  __syncthreads();
  if (t < B && h[t] > 0) base_s[t] = atomicAdd(&gcur[t], h[t]);
  cur[t] = 0;
  __syncthreads();
  for (int i = t; i < m; i += 256) {
    int b = bk[i];
    int r = atomicAdd(&cur[b], 1);
    int p = base_s[b] + r;
    if (p < cap) tmp[(size_t)b * cap + p] = pk[i];
  }
}

// ---------------- gemm tile body ----------------
template <bool AF32>
__device__ __forceinline__ void gemm_tile(SMem& sm, const void* Ap,
                                          const unsigned short* Wt,
                                          unsigned short* C, int N, int tile) {
  for (int idx = threadIdx.x; idx < 2048; idx += 256) {
    int n = idx >> 4, c = idx & 15;
    *(uint4*)&sm.ws[n * 136 + c * 8] = ((const uint4*)Wt)[idx];
  }
  __syncthreads();
  const int w = threadIdx.x >> 6;
  const int lane = threadIdx.x & 63;
  const int quad = lane >> 4, l16 = lane & 15;
  const int rb = tile * 128 + w * 32;
  f32x4 acc[2][8] = {};
  #pragma unroll
  for (int ks = 0; ks < 4; ks++) {
    short8 aF[2];
    #pragma unroll
    for (int m = 0; m < 2; m++) {
      int r = rb + m * 16 + l16;
      short8 a = {};
      if (r < N) {
        if (AF32) {
          const float* ar = (const float*)Ap + (size_t)r * 128 + ks * 32 + quad * 8;
          float4 u0 = *(const float4*)ar;
          float4 u1 = *(const float4*)(ar + 4);
          a[0] = (short)f2bf(u0.x); a[1] = (short)f2bf(u0.y);
          a[2] = (short)f2bf(u0.z); a[3] = (short)f2bf(u0.w);
          a[4] = (short)f2bf(u1.x); a[5] = (short)f2bf(u1.y);
          a[6] = (short)f2bf(u1.z); a[7] = (short)f2bf(u1.w);
        } else {
          a = *(const short8*)((const unsigned short*)Ap + (size_t)r * 128 + ks * 32 + quad * 8);
        }
      }
      aF[m] = a;
    }
    #pragma unroll
    for (int t = 0; t < 8; t++) {
      short8 bF = *(const short8*)&sm.ws[(t * 16 + l16) * 136 + ks * 32 + quad * 8];
      acc[0][t] = __builtin_amdgcn_mfma_f32_16x16x32_bf16(aF[0], bF, acc[0][t], 0, 0, 0);
      acc[1][t] = __builtin_amdgcn_mfma_f32_16x16x32_bf16(aF[1], bF, acc[1][t], 0, 0, 0);
    }
  }
  __syncthreads();
  unsigned short* Cs = sm.ws;
  #pragma unroll
  for (int m = 0; m < 2; m++) {
    int rloc = w * 32 + m * 16 + quad * 4;
    #pragma unroll
    for (int t = 0; t < 8; t++)
      #pragma unroll
      for (int rg = 0; rg < 4; rg++)
        Cs[(rloc + rg) * 132 + t * 16 + l16] = f2bf(acc[m][t][rg]);
  }
  __syncthreads();
  const int r0 = tile * 128;
  for (int idx = threadIdx.x; idx < 2048; idx += 256) {
    int row = idx >> 4, c = idx & 15;
    int rr = r0 + row;
    if (rr < N) {
      uint2 a = *(uint2*)&Cs[row * 132 + c * 8];
      uint2 b = *(uint2*)&Cs[row * 132 + c * 8 + 4];
      ((uint4*)C)[(size_t)rr * 16 + c] = make_uint4(a.x, a.y, b.x, b.y);
    }
  }
}

// ---------------- fused: cntfill (blocks [0,B)) + gemm1 (blocks [B, B+ntiles)) ----------------
__global__ __launch_bounds__(256) void cntfill_gemm1_k(const unsigned int* __restrict__ tmp,
                                                       const int* __restrict__ gcur,
                                                       int N, int E, int cap, int B,
                                                       float* __restrict__ dinv,
                                                       int* __restrict__ rs,
                                                       unsigned short* __restrict__ col,
                                                       const float* __restrict__ x,
                                                       const unsigned short* __restrict__ W1t,
                                                       unsigned short* __restrict__ B2) {
  __shared__ SMem sm;
  const int t = threadIdx.x;
  if ((int)blockIdx.x >= B) {
    gemm_tile<true>(sm, x, W1t, B2, N, blockIdx.x - B);
    return;
  }
  int b = blockIdx.x;
  int cb = 0;
  if (t < B) { cb = gcur[t]; if (cb > cap) cb = cap; }
  sm.cf.sb[t] = cb;
  __syncthreads();
  for (int off = 1; off < 256; off <<= 1) {
    int u = (t >= off) ? sm.cf.sb[t - off] : 0;
    __syncthreads();
    sm.cf.sb[t] += u;
    __syncthreads();
  }
  int base_b = (b > 0) ? sm.cf.sb[b - 1] : 0;
  int cnt_b = sm.cf.sb[b] - base_b;
  if (b == 0 && t == 0) rs[N] = sm.cf.sb[B - 1];
  const unsigned* tb = tmp + (size_t)b * cap;
  sm.cf.c[t] = 0;
  __syncthreads();
  for (int i = t; i < cnt_b; i += 256) atomicAdd(&sm.cf.c[tb[i] & 255u], 1);
  __syncthreads();
  int v = sm.cf.c[t];
  sm.cf.cur[t] = v;
  __syncthreads();
  for (int off = 1; off < 256; off <<= 1) {
    int u = (t >= off) ? sm.cf.cur[t - off] : 0;
    __syncthreads();
    sm.cf.cur[t] += u;
    __syncthreads();
  }
  int rsv = base_b + sm.cf.cur[t] - v;
  int node = (b << 8) + t;
  if (node < N) {
    rs[node] = rsv;
    dinv[node] = rsqrtf((float)v + 1.0f);
  }
  __syncthreads();
  sm.cf.cur[t] = rsv;
  __syncthreads();
  for (int i = t; i < cnt_b; i += 256) {
    unsigned u = tb[i];
    int pos = atomicAdd(&sm.cf.cur[u & 255u], 1);
    col[pos] = (unsigned short)(u >> 8);
  }
}

// standalone gemm (layer 2 + fallback layer 1)
template <bool AF32>
__global__ __launch_bounds__(256) void gemm_bf_k(const void* __restrict__ Ap,
                                                 const unsigned short* __restrict__ Wt,
                                                 unsigned short* __restrict__ C, int N) {
  __shared__ SMem sm;
  gemm_tile<AF32>(sm, Ap, Wt, C, N, blockIdx.x);
}

// ---------------- aggregation: 16 lanes/edge, 8 edges in flight (row-major bf16) ----------------
template <typename CT>
__global__ __launch_bounds__(256) void agg8_k(const unsigned short* __restrict__ h,
                                              const int* __restrict__ rs,
                                              const CT* __restrict__ col,
                                              const float* __restrict__ dinv,
                                              const float* __restrict__ bias,
                                              unsigned short* __restrict__ outp, int n) {
  int wid = (blockIdx.x * blockDim.x + threadIdx.x) >> 6;
  int lane = threadIdx.x & 63;
  if (wid >= n) return;
  const int g = lane >> 4;
  const int l = lane & 15;
  float di = dinv[wid];
  float acc[8];
  {
    uint4 sv = ((const uint4*)(h + (size_t)wid * 128))[l];
    float ws = (g == 0) ? di : 0.f;
    acc[0] = bf2f((unsigned short)sv.x) * ws;
    acc[1] = bf2f((unsigned short)(sv.x >> 16)) * ws;
    acc[2] = bf2f((unsigned short)sv.y) * ws;
    acc[3] = bf2f((unsigned short)(sv.y >> 16)) * ws;
    acc[4] = bf2f((unsigned short)sv.z) * ws;
    acc[5] = bf2f((unsigned short)(sv.z >> 16)) * ws;
    acc[6] = bf2f((unsigned short)sv.w) * ws;
    acc[7] = bf2f((unsigned short)(sv.w >> 16)) * ws;
  }
  int beg = rs[wid], end = rs[wid + 1];
  for (int base = beg; base < end; base += 8) {
    int e0 = base + g, e1 = base + 4 + g;
    int i0 = (e0 < end) ? e0 : end - 1;
    int i1 = (e1 < end) ? e1 : end - 1;
    int s0 = (int)col[i0], s1 = (int)col[i1];
    float w0 = (e0 < end) ? dinv[s0] : 0.f;
    float w1 = (e1 < end) ? dinv[s1] : 0.f;
    uint4 h0 = ((const uint4*)(h + (size_t)s0 * 128))[l];
    uint4 h1 = ((const uint4*)(h + (size_t)s1 * 128))[l];
    acc[0] += bf2f((unsigned short)h0.x) * w0 + bf2f((unsigned short)h1.x) * w1;
    acc[1] += bf2f((unsigned short)(h0.x >> 16)) * w0 + bf2f((unsigned short)(h1.x >> 16)) * w1;
    acc[2] += bf2f((unsigned short)h0.y) * w0 + bf2f((unsigned short)h1.y) * w1;
    acc[3] += bf2f((unsigned short)(h0.y >> 16)) * w0 + bf2f((unsigned short)(h1.y >> 16)) * w1;
    acc[4] += bf2f((unsigned short)h0.z) * w0 + bf2f((unsigned short)h1.z) * w1;
    acc[5] += bf2f((unsigned short)(h0.z >> 16)) * w0 + bf2f((unsigned short)(h1.z >> 16)) * w1;
    acc[6] += bf2f((unsigned short)h0.w) * w0 + bf2f((unsigned short)h1.w) * w1;
    acc[7] += bf2f((unsigned short)(h0.w >> 16)) * w0 + bf2f((unsigned short)(h1.w >> 16)) * w1;
  }
  #pragma unroll
  for (int j = 0; j < 8; j++) {
    acc[j] += __shfl_xor(acc[j], 16);
    acc[j] += __shfl_xor(acc[j], 32);
  }
  if (g == 0) {
    float4 bA = *(const float4*)(bias + l * 8);
    float4 bB = *(const float4*)(bias + l * 8 + 4);
    float r0 = fmaxf(acc[0] * di + bA.x, 0.f);
    float r1 = fmaxf(acc[1] * di + bA.y, 0.f);
    float r2 = fmaxf(acc[2] * di + bA.z, 0.f);
    float r3 = fmaxf(acc[3] * di + bA.w, 0.f);
    float r4 = fmaxf(acc[4] * di + bB.x, 0.f);
    float r5 = fmaxf(acc[5] * di + bB.y, 0.f);
    float r6 = fmaxf(acc[6] * di + bB.z, 0.f);
    float r7 = fmaxf(acc[7] * di + bB.w, 0.f);
    uint4 v;
    v.x = (unsigned)f2bf(r0) | ((unsigned)f2bf(r1) << 16);
    v.y = (unsigned)f2bf(r2) | ((unsigned)f2bf(r3) << 16);
    v.z = (unsigned)f2bf(r4) | ((unsigned)f2bf(r5) << 16);
    v.w = (unsigned)f2bf(r6) | ((unsigned)f2bf(r7) << 16);
    ((uint4*)outp)[(size_t)wid * 16 + l] = v;
  }
}

// ---------------- per-graph mean pool (bf16 input; pool zeroed in prep) ----------------
__global__ void poolb_k(const unsigned short* __restrict__ h, const int* __restrict__ batch, int n,
                        float* __restrict__ pool, float* __restrict__ gcnt) {
  int f = threadIdx.x;
  int n0 = blockIdx.x * 64;
  if (n0 >= n) return;
  int n1 = n0 + 64; if (n1 > n) n1 = n;
  int gcur = batch[n0];
  float acc = 0.f, cacc = 0.f;
  for (int i = n0; i < n1; i++) {
    int g = batch[i];
    if (g != gcur) {
      atomicAdd(&pool[gcur * 128 + f], acc);
      if (f == 0) atomicAdd(&gcnt[gcur], cacc);
      acc = 0.f; cacc = 0.f; gcur = g;
    }
    acc += bf2f(h[(size_t)i * 128 + f]);
    cacc += 1.f;
  }
  atomicAdd(&pool[gcur * 128 + f], acc);
  if (f == 0) atomicAdd(&gcnt[gcur], cacc);
}

// ---------------- classifier head ----------------
__global__ void classify_k(const float* __restrict__ pool, const float* __restrict__ gcnt,
                           const float* __restrict__ Wc1, const float* __restrict__ bc1,
                           const float* __restrict__ Wc2, const float* __restrict__ bc2,
                           float* __restrict__ out, int nc) {
  __shared__ float gs[128];
  __shared__ float zs[128];
  int g = blockIdx.x, t = threadIdx.x;
  float c = gcnt[g]; if (c < 1.f) c = 1.f;
  gs[t] = pool[g * 128 + t] / c;
  __syncthreads();
  float acc = bc1[t];
  for (int k = 0; k < 128; k++) acc += gs[k] * Wc1[k * 128 + t];
  zs[t] = fmaxf(acc, 0.f);
  __syncthreads();
  if (t < nc) {
    float o = bc2[t];
    for (int k = 0; k < 128; k++) o += zs[k] * Wc2[k * nc + t];
    out[g * nc + t] = o;
  }
}

// ---------------- fallback CSR build (N > 65535) ----------------
__global__ void count_edges_k(const int* __restrict__ dst, int E, int* __restrict__ cnt) {
  int e = blockIdx.x * blockDim.x + threadIdx.x;
  if (e < E) atomicAdd(&cnt[dst[e]], 1);
}
__global__ void dinv_k(const int* __restrict__ cnt, float* __restrict__ dinv, int n) {
  int i = blockIdx.x * blockDim.x + threadIdx.x;
  if (i < n) dinv[i] = rsqrtf((float)cnt[i] + 1.0f);
}
__global__ void fill_csr_k(const int* __restrict__ src, const int* __restrict__ dst, int E,
                           int* __restrict__ cursor, int* __restrict__ col) {
  int e = blockIdx.x * blockDim.x + threadIdx.x;
  if (e < E) {
    int d = dst[e], s = src[e];
    int pos = atomicAdd(&cursor[d], 1);
    col[pos] = s;
  }
}
__global__ void scan1_k(const int* __restrict__ cnt, int* __restrict__ rs,
                        int* __restrict__ partials, int n) {
  __shared__ int s[1024];
  int t = threadIdx.x;
  int gid = blockIdx.x * 1024 + t;
  int v = (gid < n) ? cnt[gid] : 0;
  s[t] = v;
  __syncthreads();
  for (int off = 1; off < 1024; off <<= 1) {
    int u = (t >= off) ? s[t - off] : 0;
    __syncthreads();
    s[t] += u;
    __syncthreads();
  }
  if (gid < n) rs[gid] = s[t] - v;
  if (t == 1023) partials[blockIdx.x] = s[1023];
}
__global__ void scan2_k(int* __restrict__ partials, int nb) {
  if (threadIdx.x == 0 && blockIdx.x == 0) {
    int acc = 0;
    for (int i = 0; i < nb; i++) { int v = partials[i]; partials[i] = acc; acc += v; }
  }
}
__global__ void scan3_k(int* __restrict__ rs, int* __restrict__ cursor,
                        const int* __restrict__ partials, int n, int total) {
  int gid = blockIdx.x * blockDim.x + threadIdx.x;
  if (gid < n) {
    int v = rs[gid] + partials[gid >> 10];
    rs[gid] = v;
    cursor[gid] = v;
  }
  if (gid == 0) rs[n] = total;
}

extern "C" void kernel_launch(void* const* d_in, const int* in_sizes, int n_in,
                              void* d_out, int out_size, void* d_ws, size_t ws_size,
                              hipStream_t stream) {
  const float* x   = (const float*)d_in[0];
  const int*   ei  = (const int*)d_in[1];
  const int*   bat = (const int*)d_in[2];
  const float* W1  = (const float*)d_in[3];
  const float* b1  = (const float*)d_in[4];
  const float* W2  = (const float*)d_in[5];
  const float* b2  = (const float*)d_in[6];
  const float* Wc1 = (const float*)d_in[7];
  const float* bc1 = (const float*)d_in[8];
  const float* Wc2 = (const float*)d_in[9];
  const float* bc2 = (const float*)d_in[10];
  float* out = (float*)d_out;

  const int N  = in_sizes[0] / 128;
  const int E  = in_sizes[1] / 2;
  const int NC = in_sizes[10];
  const int G  = out_size / NC;
  const int* src = ei;
  const int* dst = ei + E;
  (void)n_in; (void)ws_size;

  size_t off = 0;
  auto walloc = [&](size_t bytes) -> void* {
    void* p = (char*)d_ws + off;
    off += (bytes + 255) & ~(size_t)255;
    return p;
  };
  unsigned short* B2 = (unsigned short*)walloc((size_t)N * 128 * 2);
  unsigned short* B3 = (unsigned short*)walloc((size_t)N * 128 * 2);
  unsigned short* W1t = (unsigned short*)walloc(128 * 128 * 2);
  unsigned short* W2t = (unsigned short*)walloc(128 * 128 * 2);
  float* dinv = (float*)walloc((size_t)N * 4);
  int*   rs   = (int*)  walloc((size_t)(N + 1) * 4);
  float* pool = (float*)walloc((size_t)G * 129 * 4);
  float* gcnt = pool + (size_t)G * 128;

  const bool small = (N <= 65535);
  const int gblocks = (N + 127) / 128;
  const int aggGrid = (N + 3) / 4;

  if (small) {
    const int B    = (N + 255) >> 8;
    const int nblk = (E + CHUNK - 1) / CHUNK;
    const int cap  = (E + B - 1) / B + 2048;
    unsigned short* col = (unsigned short*)walloc((size_t)E * 2);
    unsigned int*   tmp = (unsigned int*)  walloc((size_t)B * cap * 4);
    int* gcur = (int*)walloc((size_t)B * 4);

    prep_k<<<128, 256, 0, stream>>>(W1, W2, W1t, W2t, gcur, B, pool, G * 129);
    scatter_atomic_k<<<nblk, 256, 0, stream>>>(src, dst, E, gcur, tmp, cap, B);
    cntfill_gemm1_k<<<B + gblocks, 256, 0, stream>>>(tmp, gcur, N, E, cap, B,
                                                     dinv, rs, col, x, W1t, B2);
    agg8_k<unsigned short><<<aggGrid, 256, 0, stream>>>(B2, rs, col, dinv, b1, B3, N);
    gemm_bf_k<false><<<gblocks, 256, 0, stream>>>(B3, W2t, B2, N);
    agg8_k<unsigned short><<<aggGrid, 256, 0, stream>>>(B2, rs, col, dinv, b2, B3, N);
    poolb_k<<<(N + 63) / 64, 128, 0, stream>>>(B3, bat, N, pool, gcnt);
    classify_k<<<G, 128, 0, stream>>>(pool, gcnt, Wc1, bc1, Wc2, bc2, out, NC);
  } else {
    const int nb = (N + 1023) / 1024;
    int* cnt    = (int*)walloc((size_t)N * 4);
    int* cursor = (int*)walloc((size_t)N * 4);
    int* col    = (int*)walloc((size_t)E * 4);
    int* partials = (int*)walloc(256 * 4);
    prep_k<<<128, 256, 0, stream>>>(W1, W2, W1t, W2t, cnt /*dummy*/, 0, pool, G * 129);
    hipMemsetAsync(cnt, 0, (size_t)N * 4, stream);
    count_edges_k<<<(E + 255) / 256, 256, 0, stream>>>(dst, E, cnt);
    scan1_k<<<nb, 1024, 0, stream>>>(cnt, rs, partials, N);
    scan2_k<<<1, 64, 0, stream>>>(partials, nb);
    scan3_k<<<(N + 255) / 256, 256, 0, stream>>>(rs, cursor, partials, N, E);
    dinv_k<<<(N + 255) / 256, 256, 0, stream>>>(cnt, dinv, N);
    fill_csr_k<<<(E + 255) / 256, 256, 0, stream>>>(src, dst, E, cursor, col);

    gemm_bf_k<true><<<gblocks, 256, 0, stream>>>(x, W1t, B2, N);
    agg8_k<int><<<aggGrid, 256, 0, stream>>>(B2, rs, col, dinv, b1, B3, N);
    gemm_bf_k<false><<<gblocks, 256, 0, stream>>>(B3, W2t, B2, N);
    agg8_k<int><<<aggGrid, 256, 0, stream>>>(B2, rs, col, dinv, b2, B3, N);
    poolb_k<<<(N + 63) / 64, 128, 0, stream>>>(B3, bat, N, pool, gcnt);
    classify_k<<<G, 128, 0, stream>>>(pool, gcnt, Wc1, bc1, Wc2, bc2, out, NC);
  }
}

// Round 12
// 296.812 us; speedup vs baseline: 2.7875x; 1.0154x over previous
//
#include <hip/hip_runtime.h>
#include <cstdint>
#include <cstddef>

#define CHUNK 4096

typedef __attribute__((ext_vector_type(8))) short short8;
typedef __attribute__((ext_vector_type(4))) float f32x4;

__device__ __forceinline__ float bf2f(unsigned short u) {
  return __uint_as_float(((unsigned)u) << 16);
}
__device__ __forceinline__ unsigned short f2bf(float f) {
  unsigned u = __float_as_uint(f);
  u += 0x7fffu + ((u >> 16) & 1u);   // RNE
  return (unsigned short)(u >> 16);
}

// shared-memory overlay: gemm staging vs cntfill scratch
union SMem {
  unsigned short ws[128 * 136];                          // 34816 B
  struct { int c[256]; int cur[256]; int sb[256]; } cf;  // 3 KB
};

// ---------------- prep: W transpose -> bf16 + zero gcur ----------------
__global__ void prep_k(const float* __restrict__ W1, const float* __restrict__ W2,
                       unsigned short* __restrict__ W1t, unsigned short* __restrict__ W2t,
                       int* __restrict__ gcur, int B) {
  int idx = blockIdx.x * 256 + threadIdx.x;   // grid 128
  const float* W = (idx < 16384) ? W1 : W2;
  unsigned short* Wt = (idx < 16384) ? W1t : W2t;
  int i = idx & 16383;
  int k = i >> 7, n = i & 127;
  Wt[n * 128 + k] = f2bf(W[i]);
  if (blockIdx.x == 0 && threadIdx.x < B) gcur[threadIdx.x] = 0;
}

// ---------------- single-pass bucket scatter (N <= 65535) ----------------
__global__ __launch_bounds__(256) void scatter_atomic_k(const int* __restrict__ src,
                                                        const int* __restrict__ dst, int E,
                                                        int* __restrict__ gcur,
                                                        unsigned int* __restrict__ tmp,
                                                        int cap, int B) {
  __shared__ unsigned pk[CHUNK];
  __shared__ unsigned char bk[CHUNK];
  __shared__ int h[256];
  __shared__ int cur[256];
  __shared__ int base_s[256];
  int t = threadIdx.x;
  h[t] = 0;
  __syncthreads();
  int e0 = blockIdx.x * CHUNK;
  int e1 = e0 + CHUNK; if (e1 > E) e1 = E;
  int m = e1 - e0;
  for (int i = t; i < m; i += 256) {
    int d = dst[e0 + i], s = src[e0 + i];
    int b = d >> 8;
    pk[i] = ((unsigned)s << 8) | (unsigned)(d & 255);
    bk[i] = (unsigned char)b;
    atomicAdd(&h[b], 1);
  }
  __syncthreads();
  if (t < B && h[t] > 0) base_s[t] = atomicAdd(&gcur[t], h[t]);
  cur[t] = 0;
  __syncthreads();
  for (int i = t; i < m; i += 256) {
    int b = bk[i];
    int r = atomicAdd(&cur[b], 1);
    int p = base_s[b] + r;
    if (p < cap) tmp[(size_t)b * cap + p] = pk[i];
  }
}

// ---------------- gemm tile body ----------------
template <bool AF32>
__device__ __forceinline__ void gemm_tile(SMem& sm, const void* Ap,
                                          const unsigned short* Wt,
                                          unsigned short* C, int N, int tile) {
  for (int idx = threadIdx.x; idx < 2048; idx += 256) {
    int n = idx >> 4, c = idx & 15;
    *(uint4*)&sm.ws[n * 136 + c * 8] = ((const uint4*)Wt)[idx];
  }
  __syncthreads();
  const int w = threadIdx.x >> 6;
  const int lane = threadIdx.x & 63;
  const int quad = lane >> 4, l16 = lane & 15;
  const int rb = tile * 128 + w * 32;
  f32x4 acc[2][8] = {};
  #pragma unroll
  for (int ks = 0; ks < 4; ks++) {
    short8 aF[2];
    #pragma unroll
    for (int m = 0; m < 2; m++) {
      int r = rb + m * 16 + l16;
      short8 a = {};
      if (r < N) {
        if (AF32) {
          const float* ar = (const float*)Ap + (size_t)r * 128 + ks * 32 + quad * 8;
          float4 u0 = *(const float4*)ar;
          float4 u1 = *(const float4*)(ar + 4);
          a[0] = (short)f2bf(u0.x); a[1] = (short)f2bf(u0.y);
          a[2] = (short)f2bf(u0.z); a[3] = (short)f2bf(u0.w);
          a[4] = (short)f2bf(u1.x); a[5] = (short)f2bf(u1.y);
          a[6] = (short)f2bf(u1.z); a[7] = (short)f2bf(u1.w);
        } else {
          a = *(const short8*)((const unsigned short*)Ap + (size_t)r * 128 + ks * 32 + quad * 8);
        }
      }
      aF[m] = a;
    }
    #pragma unroll
    for (int t = 0; t < 8; t++) {
      short8 bF = *(const short8*)&sm.ws[(t * 16 + l16) * 136 + ks * 32 + quad * 8];
      acc[0][t] = __builtin_amdgcn_mfma_f32_16x16x32_bf16(aF[0], bF, acc[0][t], 0, 0, 0);
      acc[1][t] = __builtin_amdgcn_mfma_f32_16x16x32_bf16(aF[1], bF, acc[1][t], 0, 0, 0);
    }
  }
  __syncthreads();
  unsigned short* Cs = sm.ws;
  #pragma unroll
  for (int m = 0; m < 2; m++) {
    int rloc = w * 32 + m * 16 + quad * 4;
    #pragma unroll
    for (int t = 0; t < 8; t++)
      #pragma unroll
      for (int rg = 0; rg < 4; rg++)
        Cs[(rloc + rg) * 132 + t * 16 + l16] = f2bf(acc[m][t][rg]);
  }
  __syncthreads();
  const int r0 = tile * 128;
  for (int idx = threadIdx.x; idx < 2048; idx += 256) {
    int row = idx >> 4, c = idx & 15;
    int rr = r0 + row;
    if (rr < N) {
      uint2 a = *(uint2*)&Cs[row * 132 + c * 8];
      uint2 b = *(uint2*)&Cs[row * 132 + c * 8 + 4];
      ((uint4*)C)[(size_t)rr * 16 + c] = make_uint4(a.x, a.y, b.x, b.y);
    }
  }
}

// ---------------- fused: cntfill (blocks [0,B)) + gemm1 (blocks [B, B+ntiles)) ----------------
__global__ __launch_bounds__(256) void cntfill_gemm1_k(const unsigned int* __restrict__ tmp,
                                                       const int* __restrict__ gcur,
                                                       int N, int E, int cap, int B,
                                                       float* __restrict__ dinv,
                                                       int* __restrict__ rs,
                                                       unsigned short* __restrict__ col,
                                                       const float* __restrict__ x,
                                                       const unsigned short* __restrict__ W1t,
                                                       unsigned short* __restrict__ B2) {
  __shared__ SMem sm;
  const int t = threadIdx.x;
  if ((int)blockIdx.x >= B) {
    gemm_tile<true>(sm, x, W1t, B2, N, blockIdx.x - B);
    return;
  }
  int b = blockIdx.x;
  int cb = 0;
  if (t < B) { cb = gcur[t]; if (cb > cap) cb = cap; }
  sm.cf.sb[t] = cb;
  __syncthreads();
  for (int off = 1; off < 256; off <<= 1) {
    int u = (t >= off) ? sm.cf.sb[t - off] : 0;
    __syncthreads();
    sm.cf.sb[t] += u;
    __syncthreads();
  }
  int base_b = (b > 0) ? sm.cf.sb[b - 1] : 0;
  int cnt_b = sm.cf.sb[b] - base_b;
  if (b == 0 && t == 0) rs[N] = sm.cf.sb[B - 1];
  const unsigned* tb = tmp + (size_t)b * cap;
  sm.cf.c[t] = 0;
  __syncthreads();
  for (int i = t; i < cnt_b; i += 256) atomicAdd(&sm.cf.c[tb[i] & 255u], 1);
  __syncthreads();
  int v = sm.cf.c[t];
  sm.cf.cur[t] = v;
  __syncthreads();
  for (int off = 1; off < 256; off <<= 1) {
    int u = (t >= off) ? sm.cf.cur[t - off] : 0;
    __syncthreads();
    sm.cf.cur[t] += u;
    __syncthreads();
  }
  int rsv = base_b + sm.cf.cur[t] - v;
  int node = (b << 8) + t;
  if (node < N) {
    rs[node] = rsv;
    dinv[node] = rsqrtf((float)v + 1.0f);
  }
  __syncthreads();
  sm.cf.cur[t] = rsv;
  __syncthreads();
  for (int i = t; i < cnt_b; i += 256) {
    unsigned u = tb[i];
    int pos = atomicAdd(&sm.cf.cur[u & 255u], 1);
    col[pos] = (unsigned short)(u >> 8);
  }
}

// standalone gemm (layer 2 + fallback layer 1)
template <bool AF32>
__global__ __launch_bounds__(256) void gemm_bf_k(const void* __restrict__ Ap,
                                                 const unsigned short* __restrict__ Wt,
                                                 unsigned short* __restrict__ C, int N) {
  __shared__ SMem sm;
  gemm_tile<AF32>(sm, Ap, Wt, C, N, blockIdx.x);
}

// ---------------- aggregation: 16 lanes/edge, 8 edges in flight (row-major bf16) ----------------
template <typename CT>
__global__ __launch_bounds__(256) void agg8_k(const unsigned short* __restrict__ h,
                                              const int* __restrict__ rs,
                                              const CT* __restrict__ col,
                                              const float* __restrict__ dinv,
                                              const float* __restrict__ bias,
                                              unsigned short* __restrict__ outp, int n) {
  int wid = (blockIdx.x * blockDim.x + threadIdx.x) >> 6;
  int lane = threadIdx.x & 63;
  if (wid >= n) return;
  const int g = lane >> 4;
  const int l = lane & 15;
  float di = dinv[wid];
  float acc[8];
  {
    uint4 sv = ((const uint4*)(h + (size_t)wid * 128))[l];
    float ws = (g == 0) ? di : 0.f;
    acc[0] = bf2f((unsigned short)sv.x) * ws;
    acc[1] = bf2f((unsigned short)(sv.x >> 16)) * ws;
    acc[2] = bf2f((unsigned short)sv.y) * ws;
    acc[3] = bf2f((unsigned short)(sv.y >> 16)) * ws;
    acc[4] = bf2f((unsigned short)sv.z) * ws;
    acc[5] = bf2f((unsigned short)(sv.z >> 16)) * ws;
    acc[6] = bf2f((unsigned short)sv.w) * ws;
    acc[7] = bf2f((unsigned short)(sv.w >> 16)) * ws;
  }
  int beg = rs[wid], end = rs[wid + 1];
  for (int base = beg; base < end; base += 8) {
    int e0 = base + g, e1 = base + 4 + g;
    int i0 = (e0 < end) ? e0 : end - 1;
    int i1 = (e1 < end) ? e1 : end - 1;
    int s0 = (int)col[i0], s1 = (int)col[i1];
    float w0 = (e0 < end) ? dinv[s0] : 0.f;
    float w1 = (e1 < end) ? dinv[s1] : 0.f;
    uint4 h0 = ((const uint4*)(h + (size_t)s0 * 128))[l];
    uint4 h1 = ((const uint4*)(h + (size_t)s1 * 128))[l];
    acc[0] += bf2f((unsigned short)h0.x) * w0 + bf2f((unsigned short)h1.x) * w1;
    acc[1] += bf2f((unsigned short)(h0.x >> 16)) * w0 + bf2f((unsigned short)(h1.x >> 16)) * w1;
    acc[2] += bf2f((unsigned short)h0.y) * w0 + bf2f((unsigned short)h1.y) * w1;
    acc[3] += bf2f((unsigned short)(h0.y >> 16)) * w0 + bf2f((unsigned short)(h1.y >> 16)) * w1;
    acc[4] += bf2f((unsigned short)h0.z) * w0 + bf2f((unsigned short)h1.z) * w1;
    acc[5] += bf2f((unsigned short)(h0.z >> 16)) * w0 + bf2f((unsigned short)(h1.z >> 16)) * w1;
    acc[6] += bf2f((unsigned short)h0.w) * w0 + bf2f((unsigned short)h1.w) * w1;
    acc[7] += bf2f((unsigned short)(h0.w >> 16)) * w0 + bf2f((unsigned short)(h1.w >> 16)) * w1;
  }
  #pragma unroll
  for (int j = 0; j < 8; j++) {
    acc[j] += __shfl_xor(acc[j], 16);
    acc[j] += __shfl_xor(acc[j], 32);
  }
  if (g == 0) {
    float4 bA = *(const float4*)(bias + l * 8);
    float4 bB = *(const float4*)(bias + l * 8 + 4);
    float r0 = fmaxf(acc[0] * di + bA.x, 0.f);
    float r1 = fmaxf(acc[1] * di + bA.y, 0.f);
    float r2 = fmaxf(acc[2] * di + bA.z, 0.f);
    float r3 = fmaxf(acc[3] * di + bA.w, 0.f);
    float r4 = fmaxf(acc[4] * di + bB.x, 0.f);
    float r5 = fmaxf(acc[5] * di + bB.y, 0.f);
    float r6 = fmaxf(acc[6] * di + bB.z, 0.f);
    float r7 = fmaxf(acc[7] * di + bB.w, 0.f);
    uint4 v;
    v.x = (unsigned)f2bf(r0) | ((unsigned)f2bf(r1) << 16);
    v.y = (unsigned)f2bf(r2) | ((unsigned)f2bf(r3) << 16);
    v.z = (unsigned)f2bf(r4) | ((unsigned)f2bf(r5) << 16);
    v.w = (unsigned)f2bf(r6) | ((unsigned)f2bf(r7) << 16);
    ((uint4*)outp)[(size_t)wid * 16 + l] = v;
  }
}

// ---------------- fused mean-pool + classifier, high-MLP version ----------------
// one block per graph; 256 threads = 16 node-slots x 16 feature-segments.
// slot s handles nodes lo+s, lo+s+16, ... ; each thread streams uint4 (8 bf16).
__global__ __launch_bounds__(256) void poolclassify2_k(const unsigned short* __restrict__ h,
                                                       const int* __restrict__ bat, int n,
                                                       const float* __restrict__ Wc1,
                                                       const float* __restrict__ bc1,
                                                       const float* __restrict__ Wc2,
                                                       const float* __restrict__ bc2,
                                                       float* __restrict__ out, int nc) {
  __shared__ float red[16][136];   // [slot][feature] (+pad)
  __shared__ float gs[128];
  __shared__ float zs[128];
  const int g = blockIdx.x;
  const int t = threadIdx.x;
  const int slot = t >> 4;        // 0..15
  const int seg = t & 15;         // feature segment: feats seg*8 .. seg*8+7
  // node range [lo, hi) via binary search (bat sorted)
  int lo;
  {
    int l = 0, r = n;
    while (l < r) { int m = (l + r) >> 1; if (bat[m] < g) l = m + 1; else r = m; }
    lo = l;
  }
  int hi;
  {
    int l = lo, r = n;
    while (l < r) { int m = (l + r) >> 1; if (bat[m] < g + 1) l = m + 1; else r = m; }
    hi = l;
  }
  float a0 = 0.f, a1 = 0.f, a2 = 0.f, a3 = 0.f, a4 = 0.f, a5 = 0.f, a6 = 0.f, a7 = 0.f;
  for (int i = lo + slot; i < hi; i += 16) {
    uint4 v = ((const uint4*)(h + (size_t)i * 128))[seg];
    a0 += bf2f((unsigned short)v.x);  a1 += bf2f((unsigned short)(v.x >> 16));
    a2 += bf2f((unsigned short)v.y);  a3 += bf2f((unsigned short)(v.y >> 16));
    a4 += bf2f((unsigned short)v.z);  a5 += bf2f((unsigned short)(v.z >> 16));
    a6 += bf2f((unsigned short)v.w);  a7 += bf2f((unsigned short)(v.w >> 16));
  }
  red[slot][seg * 8 + 0] = a0; red[slot][seg * 8 + 1] = a1;
  red[slot][seg * 8 + 2] = a2; red[slot][seg * 8 + 3] = a3;
  red[slot][seg * 8 + 4] = a4; red[slot][seg * 8 + 5] = a5;
  red[slot][seg * 8 + 6] = a6; red[slot][seg * 8 + 7] = a7;
  __syncthreads();
  if (t < 128) {
    float c = (float)(hi - lo); if (c < 1.f) c = 1.f;
    float s = 0.f;
    #pragma unroll
    for (int k = 0; k < 16; k++) s += red[k][t];
    gs[t] = s / c;
  }
  __syncthreads();
  if (t < 128) {
    float a = bc1[t];
    for (int k = 0; k < 128; k++) a += gs[k] * Wc1[k * 128 + t];
    zs[t] = fmaxf(a, 0.f);
  }
  __syncthreads();
  if (t < nc) {
    float o = bc2[t];
    for (int k = 0; k < 128; k++) o += zs[k] * Wc2[k * nc + t];
    out[g * nc + t] = o;
  }
}

// ---------------- fallback CSR build (N > 65535) ----------------
__global__ void count_edges_k(const int* __restrict__ dst, int E, int* __restrict__ cnt) {
  int e = blockIdx.x * blockDim.x + threadIdx.x;
  if (e < E) atomicAdd(&cnt[dst[e]], 1);
}
__global__ void dinv_k(const int* __restrict__ cnt, float* __restrict__ dinv, int n) {
  int i = blockIdx.x * blockDim.x + threadIdx.x;
  if (i < n) dinv[i] = rsqrtf((float)cnt[i] + 1.0f);
}
__global__ void fill_csr_k(const int* __restrict__ src, const int* __restrict__ dst, int E,
                           int* __restrict__ cursor, int* __restrict__ col) {
  int e = blockIdx.x * blockDim.x + threadIdx.x;
  if (e < E) {
    int d = dst[e], s = src[e];
    int pos = atomicAdd(&cursor[d], 1);
    col[pos] = s;
  }
}
__global__ void scan1_k(const int* __restrict__ cnt, int* __restrict__ rs,
                        int* __restrict__ partials, int n) {
  __shared__ int s[1024];
  int t = threadIdx.x;
  int gid = blockIdx.x * 1024 + t;
  int v = (gid < n) ? cnt[gid] : 0;
  s[t] = v;
  __syncthreads();
  for (int off = 1; off < 1024; off <<= 1) {
    int u = (t >= off) ? s[t - off] : 0;
    __syncthreads();
    s[t] += u;
    __syncthreads();
  }
  if (gid < n) rs[gid] = s[t] - v;
  if (t == 1023) partials[blockIdx.x] = s[1023];
}
__global__ void scan2_k(int* __restrict__ partials, int nb) {
  if (threadIdx.x == 0 && blockIdx.x == 0) {
    int acc = 0;
    for (int i = 0; i < nb; i++) { int v = partials[i]; partials[i] = acc; acc += v; }
  }
}
__global__ void scan3_k(int* __restrict__ rs, int* __restrict__ cursor,
                        const int* __restrict__ partials, int n, int total) {
  int gid = blockIdx.x * blockDim.x + threadIdx.x;
  if (gid < n) {
    int v = rs[gid] + partials[gid >> 10];
    rs[gid] = v;
    cursor[gid] = v;
  }
  if (gid == 0) rs[n] = total;
}

extern "C" void kernel_launch(void* const* d_in, const int* in_sizes, int n_in,
                              void* d_out, int out_size, void* d_ws, size_t ws_size,
                              hipStream_t stream) {
  const float* x   = (const float*)d_in[0];
  const int*   ei  = (const int*)d_in[1];
  const int*   bat = (const int*)d_in[2];
  const float* W1  = (const float*)d_in[3];
  const float* b1  = (const float*)d_in[4];
  const float* W2  = (const float*)d_in[5];
  const float* b2  = (const float*)d_in[6];
  const float* Wc1 = (const float*)d_in[7];
  const float* bc1 = (const float*)d_in[8];
  const float* Wc2 = (const float*)d_in[9];
  const float* bc2 = (const float*)d_in[10];
  float* out = (float*)d_out;

  const int N  = in_sizes[0] / 128;
  const int E  = in_sizes[1] / 2;
  const int NC = in_sizes[10];
  const int G  = out_size / NC;
  const int* src = ei;
  const int* dst = ei + E;
  (void)n_in; (void)ws_size;

  size_t off = 0;
  auto walloc = [&](size_t bytes) -> void* {
    void* p = (char*)d_ws + off;
    off += (bytes + 255) & ~(size_t)255;
    return p;
  };
  unsigned short* B2 = (unsigned short*)walloc((size_t)N * 128 * 2);
  unsigned short* B3 = (unsigned short*)walloc((size_t)N * 128 * 2);
  unsigned short* W1t = (unsigned short*)walloc(128 * 128 * 2);
  unsigned short* W2t = (unsigned short*)walloc(128 * 128 * 2);
  float* dinv = (float*)walloc((size_t)N * 4);
  int*   rs   = (int*)  walloc((size_t)(N + 1) * 4);

  const bool small = (N <= 65535);
  const int gblocks = (N + 127) / 128;
  const int aggGrid = (N + 3) / 4;

  if (small) {
    const int B    = (N + 255) >> 8;
    const int nblk = (E + CHUNK - 1) / CHUNK;
    const int cap  = (E + B - 1) / B + 2048;
    unsigned short* col = (unsigned short*)walloc((size_t)E * 2);
    unsigned int*   tmp = (unsigned int*)  walloc((size_t)B * cap * 4);
    int* gcur = (int*)walloc((size_t)B * 4);

    prep_k<<<128, 256, 0, stream>>>(W1, W2, W1t, W2t, gcur, B);
    scatter_atomic_k<<<nblk, 256, 0, stream>>>(src, dst, E, gcur, tmp, cap, B);
    cntfill_gemm1_k<<<B + gblocks, 256, 0, stream>>>(tmp, gcur, N, E, cap, B,
                                                     dinv, rs, col, x, W1t, B2);
    agg8_k<unsigned short><<<aggGrid, 256, 0, stream>>>(B2, rs, col, dinv, b1, B3, N);
    gemm_bf_k<false><<<gblocks, 256, 0, stream>>>(B3, W2t, B2, N);
    agg8_k<unsigned short><<<aggGrid, 256, 0, stream>>>(B2, rs, col, dinv, b2, B3, N);
    poolclassify2_k<<<G, 256, 0, stream>>>(B3, bat, N, Wc1, bc1, Wc2, bc2, out, NC);
  } else {
    const int nb = (N + 1023) / 1024;
    int* cnt    = (int*)walloc((size_t)N * 4);
    int* cursor = (int*)walloc((size_t)N * 4);
    int* col    = (int*)walloc((size_t)E * 4);
    int* partials = (int*)walloc(256 * 4);
    prep_k<<<128, 256, 0, stream>>>(W1, W2, W1t, W2t, cnt /*dummy*/, 0);
    hipMemsetAsync(cnt, 0, (size_t)N * 4, stream);
    count_edges_k<<<(E + 255) / 256, 256, 0, stream>>>(dst, E, cnt);
    scan1_k<<<nb, 1024, 0, stream>>>(cnt, rs, partials, N);
    scan2_k<<<1, 64, 0, stream>>>(partials, nb);
    scan3_k<<<(N + 255) / 256, 256, 0, stream>>>(rs, cursor, partials, N, E);
    dinv_k<<<(N + 255) / 256, 256, 0, stream>>>(cnt, dinv, N);
    fill_csr_k<<<(E + 255) / 256, 256, 0, stream>>>(src, dst, E, cursor, col);

    gemm_bf_k<true><<<gblocks, 256, 0, stream>>>(x, W1t, B2, N);
    agg8_k<int><<<aggGrid, 256, 0, stream>>>(B2, rs, col, dinv, b1, B3, N);
    gemm_bf_k<false><<<gblocks, 256, 0, stream>>>(B3, W2t, B2, N);
    agg8_k<int><<<aggGrid, 256, 0, stream>>>(B2, rs, col, dinv, b2, B3, N);
    poolclassify2_k<<<G, 256, 0, stream>>>(B3, bat, N, Wc1, bc1, Wc2, bc2, out, NC);
  }
}